// Round 7
// baseline (378.024 us; speedup 1.0000x reference)
//
#include <hip/hip_runtime.h>
#include <hip/hip_bf16.h>
#include <hip/hip_fp16.h>

// GATv2 3-layer, N=80000 E=1280000 FIN=128 H=64 OUT=10.
// Round 21: agg9 = agg8 + one-iteration software pipeline on the quad loop:
//   iter q issues col loads for q+1, scores quad q (hides col latency),
//   issues q+1's xlh/slp gathers, then finishes q's reduce/exp/accumulate
//   (hides gather latency). Doubles per-wave memory-level parallelism;
//   R6 showed successive quads were serialized on the col->gather chain.
// Everything else = R6 (deterministic partition, window degree sort,
// lin_mfma MFMA f16 + score decomposition, readout2).

#define NN 80000
#define EE 1280000
#define FIN 128
#define HH 64
#define OUTD 10
#define NBUK 79            // dst>>10 buckets (79*1024 >= 80000)
#define PCH 2048           // edges per partition chunk
#define NCH 625            // EE / PCH
#define WND 2000           // degree-sort window (40 * 2000 = 80000)

typedef __hip_bfloat16 bf16;
typedef _Float16 f16x8 __attribute__((ext_vector_type(8)));
typedef float f32x4 __attribute__((ext_vector_type(4)));

__device__ __forceinline__ float ldw(const void* p, int i, int f) {
    return f ? __bfloat162float(((const bf16*)p)[i]) : ((const float*)p)[i];
}

// ---------------- dtype detect ----------------
__global__ void detect_kernel(const unsigned* __restrict__ w, int* __restrict__ flag) {
    int lane = threadIdx.x;
    int big = 0;
    for (int i = lane; i < 2048; i += 64) {
        unsigned u = w[i];
        float a = __uint_as_float(u << 16);
        float b = __uint_as_float(u & 0xffff0000u);
        if (!(fabsf(a) <= 1024.f)) big = 1;
        if (!(fabsf(b) <= 1024.f)) big = 1;
    }
    big = (__ballot(big) != 0ull) ? 1 : 0;
    if (lane == 0) flag[0] = big ? 0 : 1;     // 1 = bf16 storage, 0 = fp32
}

// ---------------- preconvert weights: Wh[j*F + k] fp16 ([j][k] = B-operand) --
__global__ void preconvert(
    const void* Wl0, const void* Wr0, const void* Wl1, const void* Wr1,
    const void* Wl2, const void* Wr2,
    const void* bl0, const void* br0, const void* bl1, const void* br1,
    const void* bl2, const void* br2,
    const void* att0, const void* att1, const void* att2,
    const void* b0, const void* b1, const void* b2,
    const void* Wro, const void* bro,
    __half* Wh0, __half* Wh1, __half* Wh2, float* small,
    const int* __restrict__ flagp)
{
    const int f = flagp[0];
    int t = blockIdx.x * 256 + threadIdx.x;
    if (t < 16384) {                        // L0: j<128, k<128
        int j = t & 127, k = t >> 7;
        float v = (j < 64) ? ldw(Wl0, j * 128 + k, f) : ldw(Wr0, (j - 64) * 128 + k, f);
        Wh0[j * 128 + k] = __float2half(v);
    } else if (t < 24576) {                 // L1: j<128, k<64
        int u = t - 16384; int j = u & 127, k = u >> 7;
        float v = (j < 64) ? ldw(Wl1, j * 64 + k, f) : ldw(Wr1, (j - 64) * 64 + k, f);
        Wh1[j * 64 + k] = __float2half(v);
    } else if (t < 32768) {                 // L2
        int u = t - 24576; int j = u & 127, k = u >> 7;
        float v = (j < 64) ? ldw(Wl2, j * 64 + k, f) : ldw(Wr2, (j - 64) * 64 + k, f);
        Wh2[j * 64 + k] = __float2half(v);
    } else if (t < 34304) {
        int s = t - 32768;
        const void* BL[3] = { bl0, bl1, bl2 };
        const void* BR[3] = { br0, br1, br2 };
        const void* AT[3] = { att0, att1, att2 };
        const void* BB[3] = { b0, b1, b2 };
        float v = 0.f;
        if (s < 384) {
            int l = s / 128, r = s % 128;
            v = (r < 64) ? ldw(BL[l], r, f) : ldw(BR[l], r - 64, f);
        } else if (s < 576) {
            int q = s - 384; v = ldw(AT[q / 64], q % 64, f);
        } else if (s < 768) {
            int q = s - 576; v = ldw(BB[q / 64], q % 64, f);
        } else if (s < 1408) {
            v = ldw(Wro, s - 768, f);
        } else if (s < 1418) {
            v = ldw(bro, s - 1408, f);
        } else return;
        small[s] = v;
    }
}

// ---------------- A: per-chunk bucket histogram ----------------
__global__ __launch_bounds__(256) void chunkhist_kernel(const int* __restrict__ dst,
                                                        int* __restrict__ chunkcnt)
{
    __shared__ int h[NBUK];
    const int tid = threadIdx.x, c = blockIdx.x;
    for (int i = tid; i < NBUK; i += 256) h[i] = 0;
    __syncthreads();
    const int e0 = c * PCH + tid * 8;
    int4 a = *(const int4*)(dst + e0);
    int4 b = *(const int4*)(dst + e0 + 4);
    atomicAdd(&h[a.x >> 10], 1); atomicAdd(&h[a.y >> 10], 1);
    atomicAdd(&h[a.z >> 10], 1); atomicAdd(&h[a.w >> 10], 1);
    atomicAdd(&h[b.x >> 10], 1); atomicAdd(&h[b.y >> 10], 1);
    atomicAdd(&h[b.z >> 10], 1); atomicAdd(&h[b.w >> 10], 1);
    __syncthreads();
    for (int i = tid; i < NBUK; i += 256) chunkcnt[i * NCH + c] = h[i];
}

// ---------------- B1: per-bucket exclusive scan over chunk counts ----------
__global__ __launch_bounds__(1024) void cscan_kernel(int* __restrict__ chunkcnt,
                                                     int* __restrict__ bucket_cnt)
{
    __shared__ int s[1024];
    const int b = blockIdx.x, t = threadIdx.x;
    int v = (t < NCH) ? chunkcnt[b * NCH + t] : 0;
    s[t] = v;
    __syncthreads();
    #pragma unroll
    for (int off = 1; off < 1024; off <<= 1) {
        int u = (t >= off) ? s[t - off] : 0;
        __syncthreads();
        s[t] += u;
        __syncthreads();
    }
    if (t < NCH) chunkcnt[b * NCH + t] = s[t] - v;
    if (t == NCH - 1) bucket_cnt[b] = s[t];
}

// ---------------- B2: scan buckets -> bucket_base ----------------
__global__ void bscan_kernel(const int* __restrict__ bucket_cnt,
                             int* __restrict__ bucket_base)
{
    __shared__ int sc[128];
    const int t = threadIdx.x;
    sc[t] = (t < NBUK) ? bucket_cnt[t] : 0;
    __syncthreads();
    #pragma unroll
    for (int off = 1; off < 128; off <<= 1) {
        int v = (t >= off) ? sc[t - off] : 0;
        __syncthreads();
        sc[t] += v;
        __syncthreads();
    }
    if (t < NBUK) bucket_base[t] = (t == 0) ? 0 : sc[t - 1];
    if (t == 0) bucket_base[NBUK] = sc[NBUK - 1];
}

// ---------------- C: deterministic partition into buckets -------------------
__global__ __launch_bounds__(256) void part_kernel(const int* __restrict__ src,
                                                   const int* __restrict__ dst,
                                                   const int* __restrict__ chunkcnt,
                                                   const int* __restrict__ bucket_base,
                                                   int2* __restrict__ part)
{
    __shared__ int hcnt[NBUK];
    __shared__ int sc[128];
    __shared__ int hbase[NBUK + 1];
    __shared__ int hpos[NBUK];
    __shared__ int hgb[NBUK];
    __shared__ int2 stage[PCH];
    const int tid = threadIdx.x, c = blockIdx.x;

    for (int i = tid; i < NBUK; i += 256) hcnt[i] = 0;
    __syncthreads();

    const int e0 = c * PCH + tid * 8;
    int4 sa = *(const int4*)(src + e0);
    int4 sb = *(const int4*)(src + e0 + 4);
    int4 da = *(const int4*)(dst + e0);
    int4 db = *(const int4*)(dst + e0 + 4);
    int dv[8] = { da.x, da.y, da.z, da.w, db.x, db.y, db.z, db.w };
    int sv[8] = { sa.x, sa.y, sa.z, sa.w, sb.x, sb.y, sb.z, sb.w };
    #pragma unroll
    for (int u = 0; u < 8; u++) atomicAdd(&hcnt[dv[u] >> 10], 1);
    __syncthreads();

    if (tid < 128) sc[tid] = (tid < NBUK) ? hcnt[tid] : 0;
    __syncthreads();
    #pragma unroll
    for (int off = 1; off < 128; off <<= 1) {
        int v = (tid < 128 && tid >= off) ? sc[tid - off] : 0;
        __syncthreads();
        if (tid < 128) sc[tid] += v;
        __syncthreads();
    }
    if (tid < NBUK) {
        int b = (tid == 0) ? 0 : sc[tid - 1];
        hbase[tid] = b;
        hpos[tid] = b;
        hgb[tid] = bucket_base[tid] + chunkcnt[tid * NCH + c];
    }
    if (tid == 0) hbase[NBUK] = PCH;
    __syncthreads();

    #pragma unroll
    for (int u = 0; u < 8; u++) {
        int p = atomicAdd(&hpos[dv[u] >> 10], 1);
        stage[p] = make_int2(sv[u], dv[u]);
    }
    __syncthreads();

    for (int s = tid; s < PCH; s += 256) {
        int lo = 0, hi = NBUK;
        #pragma unroll
        for (int it = 0; it < 7; it++) {
            int mid = (lo + hi) >> 1;
            if (hbase[mid] <= s) lo = mid; else hi = mid;
        }
        part[hgb[lo] + (s - hbase[lo])] = stage[s];
    }
}

// ---------------- fine hist: one block per bucket, LDS counters -------------
__global__ __launch_bounds__(256) void hist_part_kernel(const int2* __restrict__ part,
                                                        const int* __restrict__ bucket_base,
                                                        int* __restrict__ cnt)
{
    __shared__ int lcnt[1024];
    const int b = blockIdx.x, tid = threadIdx.x;
    const int dbase = b << 10;
    for (int i = tid; i < 1024; i += 256) lcnt[i] = 0;
    __syncthreads();
    const int eb = bucket_base[b], ee = bucket_base[b + 1];
    for (int e = eb + tid; e < ee; e += 256)
        atomicAdd(&lcnt[part[e].y - dbase], 1);
    __syncthreads();
    const int nd = min(1024, NN - dbase);
    for (int i = tid; i < nd; i += 256) cnt[dbase + i] = lcnt[i];
}

// ---------------- scans ----------------
__global__ void scan1(const int* __restrict__ cnt, int* __restrict__ rowptr,
                      int* __restrict__ bsums) {
    __shared__ int sh[256];
    int i = blockIdx.x * 256 + threadIdx.x;
    int tid = threadIdx.x;
    int c = (i < NN) ? cnt[i] : 0;
    sh[tid] = c;
    __syncthreads();
    #pragma unroll
    for (int off = 1; off < 256; off <<= 1) {
        int t = (tid >= off) ? sh[tid - off] : 0;
        __syncthreads();
        sh[tid] += t;
        __syncthreads();
    }
    if (i < NN) rowptr[i + 1] = sh[tid];
    if (tid == 255) bsums[blockIdx.x] = sh[255];
}

__global__ void scan2(int* __restrict__ bsums, int nb) {
    __shared__ int sh[512];
    int t = threadIdx.x;
    sh[t] = (t < nb) ? bsums[t] : 0;
    __syncthreads();
    #pragma unroll
    for (int off = 1; off < 512; off <<= 1) {
        int v = (t >= off) ? sh[t - off] : 0;
        __syncthreads();
        sh[t] += v;
        __syncthreads();
    }
    if (t < nb) bsums[t] = sh[t];
}

__global__ void scan3(int* __restrict__ rowptr, const int* __restrict__ bsums) {
    int i = blockIdx.x * 256 + threadIdx.x;
    if (i == 0) rowptr[0] = 0;
    int add = (blockIdx.x == 0) ? 0 : bsums[blockIdx.x - 1];
    if (i < NN) rowptr[i + 1] += add;
}

// ---------------- wprep: window-local degree counting sort (all LDS) --------
// One block per 2000-node window; descending-degree order within window.
__global__ __launch_bounds__(256) void wprep_kernel(const int* __restrict__ fillc,
                                                    int* __restrict__ order)
{
    __shared__ int h[64];
    const int w0 = blockIdx.x * WND;
    const int tid = threadIdx.x;
    if (tid < 64) h[tid] = 0;
    __syncthreads();
    int bin[8];
    #pragma unroll
    for (int u = 0; u < 8; u++) {
        int t = tid + u * 256;
        if (t < WND) {
            int b = 63 - min(fillc[w0 + t], 63);   // descending degree
            bin[u] = b;
            atomicAdd(&h[b], 1);
        } else bin[u] = -1;
    }
    __syncthreads();
    if (tid == 0) {                                 // 64-bin exclusive scan
        int run = 0;
        #pragma unroll
        for (int b = 0; b < 64; b++) { int c = h[b]; h[b] = run; run += c; }
    }
    __syncthreads();
    #pragma unroll
    for (int u = 0; u < 8; u++) {
        int t = tid + u * 256;
        if (t < WND) {
            int p = atomicAdd(&h[bin[u]], 1);
            order[w0 + p] = w0 + t;
        }
    }
}

// ---------------- P2: fine scatter, one block per bucket --------------------
// col stores src only (agg never needs dst; it's implicit).
__global__ __launch_bounds__(256) void scatter2_kernel(const int2* __restrict__ part,
                                                       const int* __restrict__ bucket_base,
                                                       const int* __restrict__ rowptr,
                                                       int* __restrict__ col)
{
    __shared__ int lfill[1024];
    const int b = blockIdx.x, tid = threadIdx.x;
    const int dbase = b << 10;
    const int nd = min(1024, NN - dbase);
    for (int i = tid; i < nd; i += 256) lfill[i] = rowptr[dbase + i];
    __syncthreads();
    const int eb = bucket_base[b], ee = bucket_base[b + 1];
    for (int e = eb + tid; e < ee; e += 256) {
        int2 sd = part[e];
        int pos = atomicAdd(&lfill[sd.y - dbase], 1);
        col[pos] = sd.x;
    }
}

// ---------------- linear via MFMA f16: [64 x F] @ [F x 128] -----------------
// A staged fp16 in LDS, XOR-swizzled (octet ^= row&7). B = Wh[j][k] from L1.
// C/D: col=lane&15, row=(lane>>4)*4+reg; A: [m=lane&15][k=quad*8+j];
// B: [n=lane&15][k=quad*8+j] (k-major per lane).
// Epilogue also emits sl[i]=att@xl[i], sr[i]=att@xr[i] (score decomposition).
#define ELX_S 72           // epilogue xl row stride (fp16)
#define EXR_S 68           // epilogue xr row stride (fp32)
template<int F, bool L0>
__global__ __launch_bounds__(256) void lin_mfma(const void* __restrict__ hin_,
                                                const __half* __restrict__ Wh,
                                                const float* __restrict__ biasLR,
                                                const float* __restrict__ attf,
                                                __half* __restrict__ xlh,
                                                float* __restrict__ xr,
                                                float* __restrict__ slp,
                                                float* __restrict__ srp,
                                                const int* __restrict__ flagp)
{
    __shared__ __align__(16) char lds[64 * ELX_S * 2 + 64 * EXR_S * 4]; // 26624 B
    _Float16* xs  = (_Float16*)lds;                    // stage: 64*F fp16 (<=16KB)
    _Float16* eXL = (_Float16*)lds;                    // epilogue xl 64x72 fp16
    float*    eXR = (float*)(lds + 64 * ELX_S * 2);    // epilogue xr 64x68 fp32

    const int tid = threadIdx.x;
    const int nb = blockIdx.x * 64;
    constexpr int OPR = F / 8;     // octets per row

    // ---- stage h -> swizzled fp16 LDS ----
    if (L0 && flagp[0]) {
        const uint4* hp = (const uint4*)hin_;
        for (int c = tid; c < 64 * OPR; c += 256) {
            int row = c / OPR, oct = c % OPR;
            uint4 u = hp[((size_t)(nb + row) * F + oct * 8) >> 3];
            unsigned ww[4] = { u.x, u.y, u.z, u.w };
            _Float16 v[8];
            #pragma unroll
            for (int p = 0; p < 4; p++) {
                v[2 * p]     = (_Float16)__uint_as_float(ww[p] << 16);
                v[2 * p + 1] = (_Float16)__uint_as_float(ww[p] & 0xffff0000u);
            }
            int so = oct ^ (row & 7);
            *(f16x8*)&xs[row * F + so * 8] = *(f16x8*)v;
        }
    } else {
        const float4* hp = (const float4*)hin_;
        for (int c = tid; c < 64 * OPR; c += 256) {
            int row = c / OPR, oct = c % OPR;
            size_t base = ((size_t)(nb + row) * F + oct * 8) >> 2;
            float4 a = hp[base], b = hp[base + 1];
            _Float16 v[8] = { (_Float16)a.x, (_Float16)a.y, (_Float16)a.z, (_Float16)a.w,
                              (_Float16)b.x, (_Float16)b.y, (_Float16)b.z, (_Float16)b.w };
            int so = oct ^ (row & 7);
            *(f16x8*)&xs[row * F + so * 8] = *(f16x8*)v;
        }
    }
    __syncthreads();

    const int w = tid >> 6;
    const int lane = tid & 63;
    const int n = lane & 15;
    const int quad = lane >> 4;
    constexpr int NS = F / 32;

    f16x8 afr[NS];
    #pragma unroll
    for (int s = 0; s < NS; s++) {
        int o = (s * 4 + quad) ^ (n & 7);
        afr[s] = *(const f16x8*)&xs[(w * 16 + n) * F + o * 8];
    }
    __syncthreads();   // xs dead; LDS reused for epilogue

    const _Float16* Whf = (const _Float16*)Wh;
    #pragma unroll
    for (int ct = 0; ct < 8; ct++) {
        float bv = biasLR[ct * 16 + n];
        f32x4 acc = { bv, bv, bv, bv };
        #pragma unroll
        for (int s = 0; s < NS; s++) {
            f16x8 bfr = *(const f16x8*)&Whf[(size_t)(ct * 16 + n) * F + s * 32 + quad * 8];
            acc = __builtin_amdgcn_mfma_f32_16x16x32_f16(afr[s], bfr, acc, 0, 0, 0);
        }
        int rbase = w * 16 + quad * 4;
        if (ct < 4) {
            #pragma unroll
            for (int rg = 0; rg < 4; rg++)
                eXL[(rbase + rg) * ELX_S + ct * 16 + n] = (_Float16)acc[rg];
        } else {
            #pragma unroll
            for (int rg = 0; rg < 4; rg++)
                eXR[(rbase + rg) * EXR_S + (ct - 4) * 16 + n] = acc[rg];
        }
    }
    __syncthreads();

    // ---- vectorized writeout ----
    for (int c = tid; c < 512; c += 256) {          // xl: 64 rows x 64 fp16
        int row = c >> 3, oct = c & 7;
        *(uint4*)&xlh[(size_t)(nb + row) * 64 + oct * 8] =
            *(const uint4*)&eXL[row * ELX_S + oct * 8];
    }
    for (int c = tid; c < 1024; c += 256) {         // xr: 64 rows x 64 fp32
        int row = c >> 4, q4 = c & 15;
        *(float4*)&xr[(size_t)(nb + row) * 64 + q4 * 4] =
            *(const float4*)&eXR[row * EXR_S + q4 * 4];
    }

    // ---- per-row att dots: sl = att@xl, sr = att@xr ----
    if (tid < 64) {
        float accl = 0.f, accr = 0.f;
        #pragma unroll
        for (int o = 0; o < 8; o++) {
            f16x8 vl = *(const f16x8*)&eXL[tid * ELX_S + o * 8];
            float4 a0 = *(const float4*)(attf + o * 8);
            float4 a1 = *(const float4*)(attf + o * 8 + 4);
            float4 v0 = *(const float4*)&eXR[tid * EXR_S + o * 8];
            float4 v1 = *(const float4*)&eXR[tid * EXR_S + o * 8 + 4];
            accl = fmaf(a0.x, (float)vl[0], accl);
            accl = fmaf(a0.y, (float)vl[1], accl);
            accl = fmaf(a0.z, (float)vl[2], accl);
            accl = fmaf(a0.w, (float)vl[3], accl);
            accl = fmaf(a1.x, (float)vl[4], accl);
            accl = fmaf(a1.y, (float)vl[5], accl);
            accl = fmaf(a1.z, (float)vl[6], accl);
            accl = fmaf(a1.w, (float)vl[7], accl);
            accr = fmaf(a0.x, v0.x, accr);
            accr = fmaf(a0.y, v0.y, accr);
            accr = fmaf(a0.z, v0.z, accr);
            accr = fmaf(a0.w, v0.w, accr);
            accr = fmaf(a1.x, v1.x, accr);
            accr = fmaf(a1.y, v1.y, accr);
            accr = fmaf(a1.z, v1.z, accr);
            accr = fmaf(a1.w, v1.w, accr);
        }
        slp[nb + tid] = accl;
        srp[nb + tid] = accr;
    }
}

// ---------------- fused score+aggregate: 8 nodes/wave, pipelined quads ------
// score decomposed: e = 0.6*(sl[src]+sr[i]) + 0.4*sum_k att_k*|xl[src]+xr[i]|
#define DECODE8(U, D) { \
    float2 _f0 = __half22float2(*(__half2*)&U.x); \
    float2 _f1 = __half22float2(*(__half2*)&U.y); \
    float2 _f2 = __half22float2(*(__half2*)&U.z); \
    float2 _f3 = __half22float2(*(__half2*)&U.w); \
    D[0]=_f0.x; D[1]=_f0.y; D[2]=_f1.x; D[3]=_f1.y; \
    D[4]=_f2.x; D[5]=_f2.y; D[6]=_f3.x; D[7]=_f3.y; }

// compute one quad (data in u0..u3 / sl0..sl3) and accumulate
#define QUAD_BODY(U0, U1, U2, U3, SL0, SL1, SL2, SL3) { \
    float A[8], B[8], C[8], D[8]; \
    DECODE8(U0, A); DECODE8(U1, B); DECODE8(U2, C); DECODE8(U3, D); \
    float p0 = 0.f, p1 = 0.f, p2 = 0.f, p3 = 0.f; \
    _Pragma("unroll") \
    for (int k = 0; k < 8; k++) { \
        p0 = fmaf(att[k], fabsf(A[k] + xri[k]), p0); \
        p1 = fmaf(att[k], fabsf(B[k] + xri[k]), p1); \
        p2 = fmaf(att[k], fabsf(C[k] + xri[k]), p2); \
        p3 = fmaf(att[k], fabsf(D[k] + xri[k]), p3); \
    } \
    p0 += __shfl_xor(p0, 1, 64);  p1 += __shfl_xor(p1, 1, 64); \
    p2 += __shfl_xor(p2, 1, 64);  p3 += __shfl_xor(p3, 1, 64); \
    p0 += __shfl_xor(p0, 2, 64);  p1 += __shfl_xor(p1, 2, 64); \
    p2 += __shfl_xor(p2, 2, 64);  p3 += __shfl_xor(p3, 2, 64); \
    p0 += __shfl_xor(p0, 4, 64);  p1 += __shfl_xor(p1, 4, 64); \
    p2 += __shfl_xor(p2, 4, 64);  p3 += __shfl_xor(p3, 4, 64); \
    float w0 = __expf(fminf(fmaf(0.4f, p0, fmaf(0.6f, SL0, sri06)), 60.f)); \
    float w1 = __expf(fminf(fmaf(0.4f, p1, fmaf(0.6f, SL1, sri06)), 60.f)); \
    float w2 = __expf(fminf(fmaf(0.4f, p2, fmaf(0.6f, SL2, sri06)), 60.f)); \
    float w3 = __expf(fminf(fmaf(0.4f, p3, fmaf(0.6f, SL3, sri06)), 60.f)); \
    _Pragma("unroll") \
    for (int k = 0; k < 8; k++) { \
        acc[k] = fmaf(w0, A[k], acc[k]); \
        acc[k] = fmaf(w1, B[k], acc[k]); \
        acc[k] = fmaf(w2, C[k], acc[k]); \
        acc[k] = fmaf(w3, D[k], acc[k]); \
    } \
    denom += (w0 + w1) + (w2 + w3); \
}

__global__ __launch_bounds__(256) void agg9_kernel(const __half* __restrict__ xlh,
                                                   const float* __restrict__ xr,
                                                   const float* __restrict__ slp,
                                                   const float* __restrict__ srp,
                                                   const float* __restrict__ attf,
                                                   const float* __restrict__ bf,
                                                   const int* __restrict__ rowptr,
                                                   const int* __restrict__ col,
                                                   const int* __restrict__ order,
                                                   float* __restrict__ hout)
{
    const int lane = threadIdx.x & 63;
    const int g = lane >> 3;        // group -> node within wave
    const int r = lane & 7;         // feature octet
    const int wid = blockIdx.x * 4 + (threadIdx.x >> 6);
    const int i = order[wid * 8 + g];   // window-degree-sorted node

    float xri[8], att[8];
    {
        float4 xa = *(const float4*)(xr + (size_t)i * 64 + r * 8);
        float4 xb = *(const float4*)(xr + (size_t)i * 64 + r * 8 + 4);
        xri[0]=xa.x; xri[1]=xa.y; xri[2]=xa.z; xri[3]=xa.w;
        xri[4]=xb.x; xri[5]=xb.y; xri[6]=xb.z; xri[7]=xb.w;
        float4 aa = *(const float4*)(attf + r * 8);
        float4 ab = *(const float4*)(attf + r * 8 + 4);
        att[0]=aa.x; att[1]=aa.y; att[2]=aa.z; att[3]=aa.w;
        att[4]=ab.x; att[5]=ab.y; att[6]=ab.z; att[7]=ab.w;
    }
    const float sri06 = 0.6f * srp[i];

    // ---- self edge ----
    uint4 srow = *(const uint4*)(xlh + (size_t)i * 64 + r * 8);
    float s[8]; DECODE8(srow, s);
    float ps = 0.f;
    #pragma unroll
    for (int k = 0; k < 8; k++)
        ps = fmaf(att[k], fabsf(s[k] + xri[k]), ps);
    ps += __shfl_xor(ps, 1, 64);
    ps += __shfl_xor(ps, 2, 64);
    ps += __shfl_xor(ps, 4, 64);
    float es = fmaf(0.4f, ps, fmaf(0.6f, slp[i], sri06));
    float wself = __expf(fminf(es, 60.f));

    float acc[8];
    #pragma unroll
    for (int k = 0; k < 8; k++) acc[k] = wself * s[k];
    float denom = wself;

    const int e0 = rowptr[i], e1 = rowptr[i + 1];
    const int n = e1 - e0;
    const int nq = n >> 2;          // full quads
    int e = e0;

    // ---- software-pipelined quad loop: gathers for q+1 issued during q ----
    uint4 u0, u1, u2, u3;
    float sl0, sl1, sl2, sl3;
    if (nq > 0) {                   // prologue: load quad 0
        int s0 = col[e], s1 = col[e + 1], s2 = col[e + 2], s3 = col[e + 3];
        sl0 = slp[s0]; sl1 = slp[s1]; sl2 = slp[s2]; sl3 = slp[s3];
        u0 = *(const uint4*)(xlh + (size_t)s0 * 64 + r * 8);
        u1 = *(const uint4*)(xlh + (size_t)s1 * 64 + r * 8);
        u2 = *(const uint4*)(xlh + (size_t)s2 * 64 + r * 8);
        u3 = *(const uint4*)(xlh + (size_t)s3 * 64 + r * 8);
    }
    for (int q = 1; q < nq; q++) {
        // (1) issue next quad's col loads
        int t0 = col[e + 4], t1 = col[e + 5], t2 = col[e + 6], t3 = col[e + 7];
        // (2) decode + score current quad (hides col latency)
        float A[8], B[8], C[8], D[8];
        DECODE8(u0, A); DECODE8(u1, B); DECODE8(u2, C); DECODE8(u3, D);
        float p0 = 0.f, p1 = 0.f, p2 = 0.f, p3 = 0.f;
        #pragma unroll
        for (int k = 0; k < 8; k++) {
            p0 = fmaf(att[k], fabsf(A[k] + xri[k]), p0);
            p1 = fmaf(att[k], fabsf(B[k] + xri[k]), p1);
            p2 = fmaf(att[k], fabsf(C[k] + xri[k]), p2);
            p3 = fmaf(att[k], fabsf(D[k] + xri[k]), p3);
        }
        // (3) issue next quad's gathers (in flight through reduce/exp/acc)
        uint4 v0 = *(const uint4*)(xlh + (size_t)t0 * 64 + r * 8);
        uint4 v1 = *(const uint4*)(xlh + (size_t)t1 * 64 + r * 8);
        uint4 v2 = *(const uint4*)(xlh + (size_t)t2 * 64 + r * 8);
        uint4 v3 = *(const uint4*)(xlh + (size_t)t3 * 64 + r * 8);
        float m0 = slp[t0], m1 = slp[t1], m2 = slp[t2], m3 = slp[t3];
        // (4) finish current quad
        p0 += __shfl_xor(p0, 1, 64);  p1 += __shfl_xor(p1, 1, 64);
        p2 += __shfl_xor(p2, 1, 64);  p3 += __shfl_xor(p3, 1, 64);
        p0 += __shfl_xor(p0, 2, 64);  p1 += __shfl_xor(p1, 2, 64);
        p2 += __shfl_xor(p2, 2, 64);  p3 += __shfl_xor(p3, 2, 64);
        p0 += __shfl_xor(p0, 4, 64);  p1 += __shfl_xor(p1, 4, 64);
        p2 += __shfl_xor(p2, 4, 64);  p3 += __shfl_xor(p3, 4, 64);
        float w0 = __expf(fminf(fmaf(0.4f, p0, fmaf(0.6f, sl0, sri06)), 60.f));
        float w1 = __expf(fminf(fmaf(0.4f, p1, fmaf(0.6f, sl1, sri06)), 60.f));
        float w2 = __expf(fminf(fmaf(0.4f, p2, fmaf(0.6f, sl2, sri06)), 60.f));
        float w3 = __expf(fminf(fmaf(0.4f, p3, fmaf(0.6f, sl3, sri06)), 60.f));
        #pragma unroll
        for (int k = 0; k < 8; k++) {
            acc[k] = fmaf(w0, A[k], acc[k]);
            acc[k] = fmaf(w1, B[k], acc[k]);
            acc[k] = fmaf(w2, C[k], acc[k]);
            acc[k] = fmaf(w3, D[k], acc[k]);
        }
        denom += (w0 + w1) + (w2 + w3);
        // (5) rotate pipeline registers
        u0 = v0; u1 = v1; u2 = v2; u3 = v3;
        sl0 = m0; sl1 = m1; sl2 = m2; sl3 = m3;
        e += 4;
    }
    if (nq > 0) {                   // epilogue quad
        QUAD_BODY(u0, u1, u2, u3, sl0, sl1, sl2, sl3);
        e += 4;
    }

    // ---- 2-edge tail ----
    if (e + 2 <= e1) {
        int sa = col[e];
        int sb = col[e + 1];
        float sla = slp[sa], slb = slp[sb];
        uint4 ua = *(const uint4*)(xlh + (size_t)sa * 64 + r * 8);
        uint4 ub = *(const uint4*)(xlh + (size_t)sb * 64 + r * 8);
        float A[8], B[8];
        DECODE8(ua, A);
        DECODE8(ub, B);

        float pa = 0.f, pb = 0.f;
        #pragma unroll
        for (int k = 0; k < 8; k++) {
            pa = fmaf(att[k], fabsf(A[k] + xri[k]), pa);
            pb = fmaf(att[k], fabsf(B[k] + xri[k]), pb);
        }
        pa += __shfl_xor(pa, 1, 64);  pb += __shfl_xor(pb, 1, 64);
        pa += __shfl_xor(pa, 2, 64);  pb += __shfl_xor(pb, 2, 64);
        pa += __shfl_xor(pa, 4, 64);  pb += __shfl_xor(pb, 4, 64);

        float wa = __expf(fminf(fmaf(0.4f, pa, fmaf(0.6f, sla, sri06)), 60.f));
        float wb = __expf(fminf(fmaf(0.4f, pb, fmaf(0.6f, slb, sri06)), 60.f));

        #pragma unroll
        for (int k = 0; k < 8; k++) {
            acc[k] = fmaf(wa, A[k], acc[k]);
            acc[k] = fmaf(wb, B[k], acc[k]);
        }
        denom += wa + wb;
        e += 2;
    }

    // ---- 1-edge tail ----
    if (e < e1) {
        int sa = col[e];
        float sla = slp[sa];
        uint4 ua = *(const uint4*)(xlh + (size_t)sa * 64 + r * 8);
        float A[8];
        DECODE8(ua, A);

        float pa = 0.f;
        #pragma unroll
        for (int k = 0; k < 8; k++)
            pa = fmaf(att[k], fabsf(A[k] + xri[k]), pa);
        pa += __shfl_xor(pa, 1, 64);
        pa += __shfl_xor(pa, 2, 64);
        pa += __shfl_xor(pa, 4, 64);

        float wa = __expf(fminf(fmaf(0.4f, pa, fmaf(0.6f, sla, sri06)), 60.f));

        #pragma unroll
        for (int k = 0; k < 8; k++)
            acc[k] = fmaf(wa, A[k], acc[k]);
        denom += wa;
    }

    // ---- epilogue: every lane owns its octet; no cross-group reduce --------
    float inv = 1.f / denom;
    float4 bfa = *(const float4*)(bf + r * 8);
    float4 bfb = *(const float4*)(bf + r * 8 + 4);
    float o0 = fmaxf(fmaf(acc[0], inv, bfa.x), 0.f);
    float o1 = fmaxf(fmaf(acc[1], inv, bfa.y), 0.f);
    float o2 = fmaxf(fmaf(acc[2], inv, bfa.z), 0.f);
    float o3 = fmaxf(fmaf(acc[3], inv, bfa.w), 0.f);
    float o4 = fmaxf(fmaf(acc[4], inv, bfb.x), 0.f);
    float o5 = fmaxf(fmaf(acc[5], inv, bfb.y), 0.f);
    float o6 = fmaxf(fmaf(acc[6], inv, bfb.z), 0.f);
    float o7 = fmaxf(fmaf(acc[7], inv, bfb.w), 0.f);
    float* op = hout + (size_t)i * 64 + r * 8;
    *(float4*)(op)     = make_float4(o0, o1, o2, o3);
    *(float4*)(op + 4) = make_float4(o4, o5, o6, o7);
}

// ---------------- readout: thread-per-node serial dot, Wro^T in LDS --------
__global__ __launch_bounds__(256) void readout2_kernel(const float* __restrict__ h,
                                                       const float* __restrict__ WROf,
                                                       const float* __restrict__ brof,
                                                       void* __restrict__ out,
                                                       const int* __restrict__ flagp)
{
    __shared__ float wsh[640];   // wsh[k*10+o] = Wro[o][k]
    __shared__ float bsh[OUTD];
    const int tid = threadIdx.x;
    for (int idx = tid; idx < 640; idx += 256) {
        int k = idx / 10, o = idx % 10;
        wsh[idx] = WROf[o * 64 + k];
    }
    if (tid < OUTD) bsh[tid] = brof[tid];
    __syncthreads();

    const int i = blockIdx.x * 256 + tid;
    if (i >= NN) return;
    const int f = flagp[0];

    float res[OUTD];
    #pragma unroll
    for (int o = 0; o < OUTD; o++) res[o] = bsh[o];

    const float4* h4 = (const float4*)(h + (size_t)i * 64);
    #pragma unroll 4
    for (int c = 0; c < 16; c++) {
        float4 hv = h4[c];
        const float* wp = &wsh[c * 40];
        #pragma unroll
        for (int o = 0; o < OUTD; o++) {
            float t = fmaf(hv.x, wp[o], fmaf(hv.y, wp[10 + o],
                      fmaf(hv.z, wp[20 + o], hv.w * wp[30 + o])));
            res[o] += t;
        }
    }

    if (f) {
        bf16* op = (bf16*)out + (size_t)i * OUTD;
        #pragma unroll
        for (int o = 0; o < OUTD; o++) op[o] = __float2bfloat16(res[o]);
    } else {
        float* op = (float*)out + (size_t)i * OUTD;
        #pragma unroll
        for (int o = 0; o < OUTD; o++) op[o] = res[o];
    }
}

extern "C" void kernel_launch(void* const* d_in, const int* in_sizes, int n_in,
                              void* d_out, int out_size, void* d_ws, size_t ws_size,
                              hipStream_t stream) {
    const void* x   = d_in[0];
    const int* ei   = (const int*)d_in[1];
    const void* Wl0 = d_in[3];  const void* bl0 = d_in[4];
    const void* Wr0 = d_in[5];  const void* br0 = d_in[6];
    const void* at0 = d_in[7];  const void* b0  = d_in[8];
    const void* Wl1 = d_in[9];  const void* bl1 = d_in[10];
    const void* Wr1 = d_in[11]; const void* br1 = d_in[12];
    const void* at1 = d_in[13]; const void* b1  = d_in[14];
    const void* Wl2 = d_in[15]; const void* bl2 = d_in[16];
    const void* Wr2 = d_in[17]; const void* br2 = d_in[18];
    const void* at2 = d_in[19]; const void* b2  = d_in[20];
    const void* Wro = d_in[21]; const void* bro = d_in[22];

    const int* srcArr = ei;
    const int* dstArr = ei + EE;

    float* wf = (float*)d_ws;
    __half* Wh0  = (__half*)wf;               // 16384 halves (slot 16384 floats)
    __half* Wh1  = (__half*)(wf + 16384);     // 8192 halves
    __half* Wh2  = (__half*)(wf + 24576);     // 8192 halves
    float* small = wf + 32768;                // 1536
    int*   flag  = (int*)(wf + 34304);        // pad 64
    int*   rowptr = (int*)(wf + 34368);       // 80001 (pad 80128)
    int*   bsums  = (int*)(wf + 114496);      // 512
    int*   fillc  = (int*)(wf + 115008);      // 80000 (per-dst counts)
    int*   bucket_cnt  = (int*)(wf + 195008); // 128
    int*   bucket_base = (int*)(wf + 195136); // 128 (+1 used)
    int*   chunkcnt    = (int*)(wf + 195264); // NBUK*NCH = 49375 (pad 49472)
    int2*  part   = (int2*)(wf + 244736);     // EE int2 = 2560000 ints
    int*   col    = (int*)(wf + 2804736);     // EE ints = 1280000
    float* slp    = wf + 4084736;             // 80000
    float* srp    = wf + 4164736;             // 80000
    int*   order  = (int*)(wf + 4244736);     // 80000
    __half* xlh   = (__half*)(wf + 5364736);  // NN*64 halves = 2560000 floats
    float* xr = wf + 7924736;                 // 5120000
    float* hA = xr + (size_t)NN * 64;         // 5120000

    float* biasLR0 = small;        float* biasLR1 = small + 128; float* biasLR2 = small + 256;
    float* attf0 = small + 384;    float* attf1 = small + 448;   float* attf2 = small + 512;
    float* bf0   = small + 576;    float* bf1   = small + 640;   float* bf2   = small + 704;
    float* WROf  = small + 768;    float* brof  = small + 1408;

    detect_kernel<<<dim3(1), dim3(64), 0, stream>>>((const unsigned*)Wl0, flag);

    preconvert<<<dim3(134), dim3(256), 0, stream>>>(
        Wl0, Wr0, Wl1, Wr1, Wl2, Wr2, bl0, br0, bl1, br1, bl2, br2,
        at0, at1, at2, b0, b1, b2, Wro, bro, Wh0, Wh1, Wh2, small, flag);

    // deterministic edge sort + CSR
    chunkhist_kernel<<<dim3(NCH), dim3(256), 0, stream>>>(dstArr, chunkcnt);
    cscan_kernel<<<dim3(NBUK), dim3(1024), 0, stream>>>(chunkcnt, bucket_cnt);
    bscan_kernel<<<dim3(1), dim3(128), 0, stream>>>(bucket_cnt, bucket_base);
    part_kernel<<<dim3(NCH), dim3(256), 0, stream>>>(srcArr, dstArr, chunkcnt, bucket_base, part);
    hist_part_kernel<<<dim3(NBUK), dim3(256), 0, stream>>>(part, bucket_base, fillc);
    scan1<<<dim3(313), dim3(256), 0, stream>>>(fillc, rowptr, bsums);
    scan2<<<dim3(1), dim3(512), 0, stream>>>(bsums, 313);
    scan3<<<dim3(313), dim3(256), 0, stream>>>(rowptr, bsums);
    wprep_kernel<<<dim3(NN / WND), dim3(256), 0, stream>>>(fillc, order);
    scatter2_kernel<<<dim3(NBUK), dim3(256), 0, stream>>>(part, bucket_base, rowptr, col);

    // layer 0
    lin_mfma<128, true><<<dim3(NN / 64), dim3(256), 0, stream>>>(x, Wh0, biasLR0, attf0, xlh, xr, slp, srp, flag);
    agg9_kernel<<<dim3(NN / 32), dim3(256), 0, stream>>>(xlh, xr, slp, srp, attf0, bf0, rowptr, col, order, hA);
    // layer 1
    lin_mfma<64, false><<<dim3(NN / 64), dim3(256), 0, stream>>>(hA, Wh1, biasLR1, attf1, xlh, xr, slp, srp, flag);
    agg9_kernel<<<dim3(NN / 32), dim3(256), 0, stream>>>(xlh, xr, slp, srp, attf1, bf1, rowptr, col, order, hA);
    // layer 2
    lin_mfma<64, false><<<dim3(NN / 64), dim3(256), 0, stream>>>(hA, Wh2, biasLR2, attf2, xlh, xr, slp, srp, flag);
    agg9_kernel<<<dim3(NN / 32), dim3(256), 0, stream>>>(xlh, xr, slp, srp, attf2, bf2, rowptr, col, order, hA);

    // readout (thread-per-node serial dot)
    readout2_kernel<<<dim3(313), dim3(256), 0, stream>>>(hA, WROf, brof, d_out, flag);
}

// Round 9
// 370.197 us; speedup vs baseline: 1.0211x; 1.0211x over previous
//
#include <hip/hip_runtime.h>
#include <hip/hip_bf16.h>
#include <hip/hip_fp16.h>

// GATv2 3-layer, N=80000 E=1280000 FIN=128 H=64 OUT=10.
// Round 23 (= R22 bugfix): readout fused into layer-2 agg.
//   R8 FAILED because wsh_/bsh_ were declared in TWO block scopes (staged
//   one shared object, read another, uninitialized). Now declared once at
//   function scope; staged iff LAST; same object read in epilogue.
// agg9 pipeline kept. Rest = R7.

#define NN 80000
#define EE 1280000
#define FIN 128
#define HH 64
#define OUTD 10
#define NBUK 79            // dst>>10 buckets (79*1024 >= 80000)
#define PCH 2048           // edges per partition chunk
#define NCH 625            // EE / PCH
#define WND 2000           // degree-sort window (40 * 2000 = 80000)

typedef __hip_bfloat16 bf16;
typedef _Float16 f16x8 __attribute__((ext_vector_type(8)));
typedef float f32x4 __attribute__((ext_vector_type(4)));

__device__ __forceinline__ float ldw(const void* p, int i, int f) {
    return f ? __bfloat162float(((const bf16*)p)[i]) : ((const float*)p)[i];
}

// ---------------- dtype detect ----------------
__global__ void detect_kernel(const unsigned* __restrict__ w, int* __restrict__ flag) {
    int lane = threadIdx.x;
    int big = 0;
    for (int i = lane; i < 2048; i += 64) {
        unsigned u = w[i];
        float a = __uint_as_float(u << 16);
        float b = __uint_as_float(u & 0xffff0000u);
        if (!(fabsf(a) <= 1024.f)) big = 1;
        if (!(fabsf(b) <= 1024.f)) big = 1;
    }
    big = (__ballot(big) != 0ull) ? 1 : 0;
    if (lane == 0) flag[0] = big ? 0 : 1;     // 1 = bf16 storage, 0 = fp32
}

// ---------------- preconvert weights: Wh[j*F + k] fp16 ([j][k] = B-operand) --
__global__ void preconvert(
    const void* Wl0, const void* Wr0, const void* Wl1, const void* Wr1,
    const void* Wl2, const void* Wr2,
    const void* bl0, const void* br0, const void* bl1, const void* br1,
    const void* bl2, const void* br2,
    const void* att0, const void* att1, const void* att2,
    const void* b0, const void* b1, const void* b2,
    const void* Wro, const void* bro,
    __half* Wh0, __half* Wh1, __half* Wh2, float* small,
    const int* __restrict__ flagp)
{
    const int f = flagp[0];
    int t = blockIdx.x * 256 + threadIdx.x;
    if (t < 16384) {                        // L0: j<128, k<128
        int j = t & 127, k = t >> 7;
        float v = (j < 64) ? ldw(Wl0, j * 128 + k, f) : ldw(Wr0, (j - 64) * 128 + k, f);
        Wh0[j * 128 + k] = __float2half(v);
    } else if (t < 24576) {                 // L1: j<128, k<64
        int u = t - 16384; int j = u & 127, k = u >> 7;
        float v = (j < 64) ? ldw(Wl1, j * 64 + k, f) : ldw(Wr1, (j - 64) * 64 + k, f);
        Wh1[j * 64 + k] = __float2half(v);
    } else if (t < 32768) {                 // L2
        int u = t - 24576; int j = u & 127, k = u >> 7;
        float v = (j < 64) ? ldw(Wl2, j * 64 + k, f) : ldw(Wr2, (j - 64) * 64 + k, f);
        Wh2[j * 64 + k] = __float2half(v);
    } else if (t < 34304) {
        int s = t - 32768;
        const void* BL[3] = { bl0, bl1, bl2 };
        const void* BR[3] = { br0, br1, br2 };
        const void* AT[3] = { att0, att1, att2 };
        const void* BB[3] = { b0, b1, b2 };
        float v = 0.f;
        if (s < 384) {
            int l = s / 128, r = s % 128;
            v = (r < 64) ? ldw(BL[l], r, f) : ldw(BR[l], r - 64, f);
        } else if (s < 576) {
            int q = s - 384; v = ldw(AT[q / 64], q % 64, f);
        } else if (s < 768) {
            int q = s - 576; v = ldw(BB[q / 64], q % 64, f);
        } else if (s < 1408) {
            v = ldw(Wro, s - 768, f);
        } else if (s < 1418) {
            v = ldw(bro, s - 1408, f);
        } else return;
        small[s] = v;
    }
}

// ---------------- A: per-chunk bucket histogram ----------------
__global__ __launch_bounds__(256) void chunkhist_kernel(const int* __restrict__ dst,
                                                        int* __restrict__ chunkcnt)
{
    __shared__ int h[NBUK];
    const int tid = threadIdx.x, c = blockIdx.x;
    for (int i = tid; i < NBUK; i += 256) h[i] = 0;
    __syncthreads();
    const int e0 = c * PCH + tid * 8;
    int4 a = *(const int4*)(dst + e0);
    int4 b = *(const int4*)(dst + e0 + 4);
    atomicAdd(&h[a.x >> 10], 1); atomicAdd(&h[a.y >> 10], 1);
    atomicAdd(&h[a.z >> 10], 1); atomicAdd(&h[a.w >> 10], 1);
    atomicAdd(&h[b.x >> 10], 1); atomicAdd(&h[b.y >> 10], 1);
    atomicAdd(&h[b.z >> 10], 1); atomicAdd(&h[b.w >> 10], 1);
    __syncthreads();
    for (int i = tid; i < NBUK; i += 256) chunkcnt[i * NCH + c] = h[i];
}

// ---------------- B1: per-bucket exclusive scan over chunk counts ----------
__global__ __launch_bounds__(1024) void cscan_kernel(int* __restrict__ chunkcnt,
                                                     int* __restrict__ bucket_cnt)
{
    __shared__ int s[1024];
    const int b = blockIdx.x, t = threadIdx.x;
    int v = (t < NCH) ? chunkcnt[b * NCH + t] : 0;
    s[t] = v;
    __syncthreads();
    #pragma unroll
    for (int off = 1; off < 1024; off <<= 1) {
        int u = (t >= off) ? s[t - off] : 0;
        __syncthreads();
        s[t] += u;
        __syncthreads();
    }
    if (t < NCH) chunkcnt[b * NCH + t] = s[t] - v;
    if (t == NCH - 1) bucket_cnt[b] = s[t];
}

// ---------------- B2: scan buckets -> bucket_base ----------------
__global__ void bscan_kernel(const int* __restrict__ bucket_cnt,
                             int* __restrict__ bucket_base)
{
    __shared__ int sc[128];
    const int t = threadIdx.x;
    sc[t] = (t < NBUK) ? bucket_cnt[t] : 0;
    __syncthreads();
    #pragma unroll
    for (int off = 1; off < 128; off <<= 1) {
        int v = (t >= off) ? sc[t - off] : 0;
        __syncthreads();
        sc[t] += v;
        __syncthreads();
    }
    if (t < NBUK) bucket_base[t] = (t == 0) ? 0 : sc[t - 1];
    if (t == 0) bucket_base[NBUK] = sc[NBUK - 1];
}

// ---------------- C: deterministic partition into buckets -------------------
__global__ __launch_bounds__(256) void part_kernel(const int* __restrict__ src,
                                                   const int* __restrict__ dst,
                                                   const int* __restrict__ chunkcnt,
                                                   const int* __restrict__ bucket_base,
                                                   int2* __restrict__ part)
{
    __shared__ int hcnt[NBUK];
    __shared__ int sc[128];
    __shared__ int hbase[NBUK + 1];
    __shared__ int hpos[NBUK];
    __shared__ int hgb[NBUK];
    __shared__ int2 stage[PCH];
    const int tid = threadIdx.x, c = blockIdx.x;

    for (int i = tid; i < NBUK; i += 256) hcnt[i] = 0;
    __syncthreads();

    const int e0 = c * PCH + tid * 8;
    int4 sa = *(const int4*)(src + e0);
    int4 sb = *(const int4*)(src + e0 + 4);
    int4 da = *(const int4*)(dst + e0);
    int4 db = *(const int4*)(dst + e0 + 4);
    int dv[8] = { da.x, da.y, da.z, da.w, db.x, db.y, db.z, db.w };
    int sv[8] = { sa.x, sa.y, sa.z, sa.w, sb.x, sb.y, sb.z, sb.w };
    #pragma unroll
    for (int u = 0; u < 8; u++) atomicAdd(&hcnt[dv[u] >> 10], 1);
    __syncthreads();

    if (tid < 128) sc[tid] = (tid < NBUK) ? hcnt[tid] : 0;
    __syncthreads();
    #pragma unroll
    for (int off = 1; off < 128; off <<= 1) {
        int v = (tid < 128 && tid >= off) ? sc[tid - off] : 0;
        __syncthreads();
        if (tid < 128) sc[tid] += v;
        __syncthreads();
    }
    if (tid < NBUK) {
        int b = (tid == 0) ? 0 : sc[tid - 1];
        hbase[tid] = b;
        hpos[tid] = b;
        hgb[tid] = bucket_base[tid] + chunkcnt[tid * NCH + c];
    }
    if (tid == 0) hbase[NBUK] = PCH;
    __syncthreads();

    #pragma unroll
    for (int u = 0; u < 8; u++) {
        int p = atomicAdd(&hpos[dv[u] >> 10], 1);
        stage[p] = make_int2(sv[u], dv[u]);
    }
    __syncthreads();

    for (int s = tid; s < PCH; s += 256) {
        int lo = 0, hi = NBUK;
        #pragma unroll
        for (int it = 0; it < 7; it++) {
            int mid = (lo + hi) >> 1;
            if (hbase[mid] <= s) lo = mid; else hi = mid;
        }
        part[hgb[lo] + (s - hbase[lo])] = stage[s];
    }
}

// ---------------- fine hist: one block per bucket, LDS counters -------------
__global__ __launch_bounds__(256) void hist_part_kernel(const int2* __restrict__ part,
                                                        const int* __restrict__ bucket_base,
                                                        int* __restrict__ cnt)
{
    __shared__ int lcnt[1024];
    const int b = blockIdx.x, tid = threadIdx.x;
    const int dbase = b << 10;
    for (int i = tid; i < 1024; i += 256) lcnt[i] = 0;
    __syncthreads();
    const int eb = bucket_base[b], ee = bucket_base[b + 1];
    for (int e = eb + tid; e < ee; e += 256)
        atomicAdd(&lcnt[part[e].y - dbase], 1);
    __syncthreads();
    const int nd = min(1024, NN - dbase);
    for (int i = tid; i < nd; i += 256) cnt[dbase + i] = lcnt[i];
}

// ---------------- scans ----------------
__global__ void scan1(const int* __restrict__ cnt, int* __restrict__ rowptr,
                      int* __restrict__ bsums) {
    __shared__ int sh[256];
    int i = blockIdx.x * 256 + threadIdx.x;
    int tid = threadIdx.x;
    int c = (i < NN) ? cnt[i] : 0;
    sh[tid] = c;
    __syncthreads();
    #pragma unroll
    for (int off = 1; off < 256; off <<= 1) {
        int t = (tid >= off) ? sh[tid - off] : 0;
        __syncthreads();
        sh[tid] += t;
        __syncthreads();
    }
    if (i < NN) rowptr[i + 1] = sh[tid];
    if (tid == 255) bsums[blockIdx.x] = sh[255];
}

__global__ void scan2(int* __restrict__ bsums, int nb) {
    __shared__ int sh[512];
    int t = threadIdx.x;
    sh[t] = (t < nb) ? bsums[t] : 0;
    __syncthreads();
    #pragma unroll
    for (int off = 1; off < 512; off <<= 1) {
        int v = (t >= off) ? sh[t - off] : 0;
        __syncthreads();
        sh[t] += v;
        __syncthreads();
    }
    if (t < nb) bsums[t] = sh[t];
}

__global__ void scan3(int* __restrict__ rowptr, const int* __restrict__ bsums) {
    int i = blockIdx.x * 256 + threadIdx.x;
    if (i == 0) rowptr[0] = 0;
    int add = (blockIdx.x == 0) ? 0 : bsums[blockIdx.x - 1];
    if (i < NN) rowptr[i + 1] += add;
}

// ---------------- wprep: window-local degree counting sort (all LDS) --------
// One block per 2000-node window; descending-degree order within window.
__global__ __launch_bounds__(256) void wprep_kernel(const int* __restrict__ fillc,
                                                    int* __restrict__ order)
{
    __shared__ int h[64];
    const int w0 = blockIdx.x * WND;
    const int tid = threadIdx.x;
    if (tid < 64) h[tid] = 0;
    __syncthreads();
    int bin[8];
    #pragma unroll
    for (int u = 0; u < 8; u++) {
        int t = tid + u * 256;
        if (t < WND) {
            int b = 63 - min(fillc[w0 + t], 63);   // descending degree
            bin[u] = b;
            atomicAdd(&h[b], 1);
        } else bin[u] = -1;
    }
    __syncthreads();
    if (tid == 0) {                                 // 64-bin exclusive scan
        int run = 0;
        #pragma unroll
        for (int b = 0; b < 64; b++) { int c = h[b]; h[b] = run; run += c; }
    }
    __syncthreads();
    #pragma unroll
    for (int u = 0; u < 8; u++) {
        int t = tid + u * 256;
        if (t < WND) {
            int p = atomicAdd(&h[bin[u]], 1);
            order[w0 + p] = w0 + t;
        }
    }
}

// ---------------- P2: fine scatter, one block per bucket --------------------
// col stores src only (agg never needs dst; it's implicit).
__global__ __launch_bounds__(256) void scatter2_kernel(const int2* __restrict__ part,
                                                       const int* __restrict__ bucket_base,
                                                       const int* __restrict__ rowptr,
                                                       int* __restrict__ col)
{
    __shared__ int lfill[1024];
    const int b = blockIdx.x, tid = threadIdx.x;
    const int dbase = b << 10;
    const int nd = min(1024, NN - dbase);
    for (int i = tid; i < nd; i += 256) lfill[i] = rowptr[dbase + i];
    __syncthreads();
    const int eb = bucket_base[b], ee = bucket_base[b + 1];
    for (int e = eb + tid; e < ee; e += 256) {
        int2 sd = part[e];
        int pos = atomicAdd(&lfill[sd.y - dbase], 1);
        col[pos] = sd.x;
    }
}

// ---------------- linear via MFMA f16: [64 x F] @ [F x 128] -----------------
// A staged fp16 in LDS, XOR-swizzled (octet ^= row&7). B = Wh[j][k] from L1.
// C/D: col=lane&15, row=(lane>>4)*4+reg; A: [m=lane&15][k=quad*8+j];
// B: [n=lane&15][k=quad*8+j] (k-major per lane).
// Epilogue also emits sl[i]=att@xl[i], sr[i]=att@xr[i] (score decomposition).
#define ELX_S 72           // epilogue xl row stride (fp16)
#define EXR_S 68           // epilogue xr row stride (fp32)
template<int F, bool L0>
__global__ __launch_bounds__(256) void lin_mfma(const void* __restrict__ hin_,
                                                const __half* __restrict__ Wh,
                                                const float* __restrict__ biasLR,
                                                const float* __restrict__ attf,
                                                __half* __restrict__ xlh,
                                                float* __restrict__ xr,
                                                float* __restrict__ slp,
                                                float* __restrict__ srp,
                                                const int* __restrict__ flagp)
{
    __shared__ __align__(16) char lds[64 * ELX_S * 2 + 64 * EXR_S * 4]; // 26624 B
    _Float16* xs  = (_Float16*)lds;                    // stage: 64*F fp16 (<=16KB)
    _Float16* eXL = (_Float16*)lds;                    // epilogue xl 64x72 fp16
    float*    eXR = (float*)(lds + 64 * ELX_S * 2);    // epilogue xr 64x68 fp32

    const int tid = threadIdx.x;
    const int nb = blockIdx.x * 64;
    constexpr int OPR = F / 8;     // octets per row

    // ---- stage h -> swizzled fp16 LDS ----
    if (L0 && flagp[0]) {
        const uint4* hp = (const uint4*)hin_;
        for (int c = tid; c < 64 * OPR; c += 256) {
            int row = c / OPR, oct = c % OPR;
            uint4 u = hp[((size_t)(nb + row) * F + oct * 8) >> 3];
            unsigned ww[4] = { u.x, u.y, u.z, u.w };
            _Float16 v[8];
            #pragma unroll
            for (int p = 0; p < 4; p++) {
                v[2 * p]     = (_Float16)__uint_as_float(ww[p] << 16);
                v[2 * p + 1] = (_Float16)__uint_as_float(ww[p] & 0xffff0000u);
            }
            int so = oct ^ (row & 7);
            *(f16x8*)&xs[row * F + so * 8] = *(f16x8*)v;
        }
    } else {
        const float4* hp = (const float4*)hin_;
        for (int c = tid; c < 64 * OPR; c += 256) {
            int row = c / OPR, oct = c % OPR;
            size_t base = ((size_t)(nb + row) * F + oct * 8) >> 2;
            float4 a = hp[base], b = hp[base + 1];
            _Float16 v[8] = { (_Float16)a.x, (_Float16)a.y, (_Float16)a.z, (_Float16)a.w,
                              (_Float16)b.x, (_Float16)b.y, (_Float16)b.z, (_Float16)b.w };
            int so = oct ^ (row & 7);
            *(f16x8*)&xs[row * F + so * 8] = *(f16x8*)v;
        }
    }
    __syncthreads();

    const int w = tid >> 6;
    const int lane = tid & 63;
    const int n = lane & 15;
    const int quad = lane >> 4;
    constexpr int NS = F / 32;

    f16x8 afr[NS];
    #pragma unroll
    for (int s = 0; s < NS; s++) {
        int o = (s * 4 + quad) ^ (n & 7);
        afr[s] = *(const f16x8*)&xs[(w * 16 + n) * F + o * 8];
    }
    __syncthreads();   // xs dead; LDS reused for epilogue

    const _Float16* Whf = (const _Float16*)Wh;
    #pragma unroll
    for (int ct = 0; ct < 8; ct++) {
        float bv = biasLR[ct * 16 + n];
        f32x4 acc = { bv, bv, bv, bv };
        #pragma unroll
        for (int s = 0; s < NS; s++) {
            f16x8 bfr = *(const f16x8*)&Whf[(size_t)(ct * 16 + n) * F + s * 32 + quad * 8];
            acc = __builtin_amdgcn_mfma_f32_16x16x32_f16(afr[s], bfr, acc, 0, 0, 0);
        }
        int rbase = w * 16 + quad * 4;
        if (ct < 4) {
            #pragma unroll
            for (int rg = 0; rg < 4; rg++)
                eXL[(rbase + rg) * ELX_S + ct * 16 + n] = (_Float16)acc[rg];
        } else {
            #pragma unroll
            for (int rg = 0; rg < 4; rg++)
                eXR[(rbase + rg) * EXR_S + (ct - 4) * 16 + n] = acc[rg];
        }
    }
    __syncthreads();

    // ---- vectorized writeout ----
    for (int c = tid; c < 512; c += 256) {          // xl: 64 rows x 64 fp16
        int row = c >> 3, oct = c & 7;
        *(uint4*)&xlh[(size_t)(nb + row) * 64 + oct * 8] =
            *(const uint4*)&eXL[row * ELX_S + oct * 8];
    }
    for (int c = tid; c < 1024; c += 256) {         // xr: 64 rows x 64 fp32
        int row = c >> 4, q4 = c & 15;
        *(float4*)&xr[(size_t)(nb + row) * 64 + q4 * 4] =
            *(const float4*)&eXR[row * EXR_S + q4 * 4];
    }

    // ---- per-row att dots: sl = att@xl, sr = att@xr ----
    if (tid < 64) {
        float accl = 0.f, accr = 0.f;
        #pragma unroll
        for (int o = 0; o < 8; o++) {
            f16x8 vl = *(const f16x8*)&eXL[tid * ELX_S + o * 8];
            float4 a0 = *(const float4*)(attf + o * 8);
            float4 a1 = *(const float4*)(attf + o * 8 + 4);
            float4 v0 = *(const float4*)&eXR[tid * EXR_S + o * 8];
            float4 v1 = *(const float4*)&eXR[tid * EXR_S + o * 8 + 4];
            accl = fmaf(a0.x, (float)vl[0], accl);
            accl = fmaf(a0.y, (float)vl[1], accl);
            accl = fmaf(a0.z, (float)vl[2], accl);
            accl = fmaf(a0.w, (float)vl[3], accl);
            accl = fmaf(a1.x, (float)vl[4], accl);
            accl = fmaf(a1.y, (float)vl[5], accl);
            accl = fmaf(a1.z, (float)vl[6], accl);
            accl = fmaf(a1.w, (float)vl[7], accl);
            accr = fmaf(a0.x, v0.x, accr);
            accr = fmaf(a0.y, v0.y, accr);
            accr = fmaf(a0.z, v0.z, accr);
            accr = fmaf(a0.w, v0.w, accr);
            accr = fmaf(a1.x, v1.x, accr);
            accr = fmaf(a1.y, v1.y, accr);
            accr = fmaf(a1.z, v1.z, accr);
            accr = fmaf(a1.w, v1.w, accr);
        }
        slp[nb + tid] = accl;
        srp[nb + tid] = accr;
    }
}

// ---------------- fused score+aggregate (+ optional fused readout) ----------
// score decomposed: e = 0.6*(sl[src]+sr[i]) + 0.4*sum_k att_k*|xl[src]+xr[i]|
#define DECODE8(U, D) { \
    float2 _f0 = __half22float2(*(__half2*)&U.x); \
    float2 _f1 = __half22float2(*(__half2*)&U.y); \
    float2 _f2 = __half22float2(*(__half2*)&U.z); \
    float2 _f3 = __half22float2(*(__half2*)&U.w); \
    D[0]=_f0.x; D[1]=_f0.y; D[2]=_f1.x; D[3]=_f1.y; \
    D[4]=_f2.x; D[5]=_f2.y; D[6]=_f3.x; D[7]=_f3.y; }

// compute one quad (data in u0..u3 / sl0..sl3) and accumulate
#define QUAD_BODY(U0, U1, U2, U3, SL0, SL1, SL2, SL3) { \
    float A[8], B[8], C[8], D[8]; \
    DECODE8(U0, A); DECODE8(U1, B); DECODE8(U2, C); DECODE8(U3, D); \
    float p0 = 0.f, p1 = 0.f, p2 = 0.f, p3 = 0.f; \
    _Pragma("unroll") \
    for (int k = 0; k < 8; k++) { \
        p0 = fmaf(att[k], fabsf(A[k] + xri[k]), p0); \
        p1 = fmaf(att[k], fabsf(B[k] + xri[k]), p1); \
        p2 = fmaf(att[k], fabsf(C[k] + xri[k]), p2); \
        p3 = fmaf(att[k], fabsf(D[k] + xri[k]), p3); \
    } \
    p0 += __shfl_xor(p0, 1, 64);  p1 += __shfl_xor(p1, 1, 64); \
    p2 += __shfl_xor(p2, 1, 64);  p3 += __shfl_xor(p3, 1, 64); \
    p0 += __shfl_xor(p0, 2, 64);  p1 += __shfl_xor(p1, 2, 64); \
    p2 += __shfl_xor(p2, 2, 64);  p3 += __shfl_xor(p3, 2, 64); \
    p0 += __shfl_xor(p0, 4, 64);  p1 += __shfl_xor(p1, 4, 64); \
    p2 += __shfl_xor(p2, 4, 64);  p3 += __shfl_xor(p3, 4, 64); \
    float w0 = __expf(fminf(fmaf(0.4f, p0, fmaf(0.6f, SL0, sri06)), 60.f)); \
    float w1 = __expf(fminf(fmaf(0.4f, p1, fmaf(0.6f, SL1, sri06)), 60.f)); \
    float w2 = __expf(fminf(fmaf(0.4f, p2, fmaf(0.6f, SL2, sri06)), 60.f)); \
    float w3 = __expf(fminf(fmaf(0.4f, p3, fmaf(0.6f, SL3, sri06)), 60.f)); \
    _Pragma("unroll") \
    for (int k = 0; k < 8; k++) { \
        acc[k] = fmaf(w0, A[k], acc[k]); \
        acc[k] = fmaf(w1, B[k], acc[k]); \
        acc[k] = fmaf(w2, C[k], acc[k]); \
        acc[k] = fmaf(w3, D[k], acc[k]); \
    } \
    denom += (w0 + w1) + (w2 + w3); \
}

template<int LAST>
__global__ __launch_bounds__(256) void agg9_kernel(const __half* __restrict__ xlh,
                                                   const float* __restrict__ xr,
                                                   const float* __restrict__ slp,
                                                   const float* __restrict__ srp,
                                                   const float* __restrict__ attf,
                                                   const float* __restrict__ bf,
                                                   const int* __restrict__ rowptr,
                                                   const int* __restrict__ col,
                                                   const int* __restrict__ order,
                                                   float* __restrict__ hout,
                                                   const float* __restrict__ WROf,
                                                   const float* __restrict__ brof,
                                                   void* __restrict__ out,
                                                   const int* __restrict__ flagp)
{
    // single function-scope shared objects (R8 bug: two block-scope copies)
    __shared__ float wsh_[640];      // Wro [o*64+k]
    __shared__ float bsh_[OUTD];

    const int lane = threadIdx.x & 63;
    const int g = lane >> 3;        // group -> node within wave
    const int r = lane & 7;         // feature octet
    const int wid = blockIdx.x * 4 + (threadIdx.x >> 6);
    const int i = order[wid * 8 + g];   // window-degree-sorted node

    if constexpr (LAST) {
        for (int idx = threadIdx.x; idx < 640; idx += 256) wsh_[idx] = WROf[idx];
        if (threadIdx.x < OUTD) bsh_[threadIdx.x] = brof[threadIdx.x];
        __syncthreads();
    }

    float xri[8], att[8];
    {
        float4 xa = *(const float4*)(xr + (size_t)i * 64 + r * 8);
        float4 xb = *(const float4*)(xr + (size_t)i * 64 + r * 8 + 4);
        xri[0]=xa.x; xri[1]=xa.y; xri[2]=xa.z; xri[3]=xa.w;
        xri[4]=xb.x; xri[5]=xb.y; xri[6]=xb.z; xri[7]=xb.w;
        float4 aa = *(const float4*)(attf + r * 8);
        float4 ab = *(const float4*)(attf + r * 8 + 4);
        att[0]=aa.x; att[1]=aa.y; att[2]=aa.z; att[3]=aa.w;
        att[4]=ab.x; att[5]=ab.y; att[6]=ab.z; att[7]=ab.w;
    }
    const float sri06 = 0.6f * srp[i];

    // ---- self edge ----
    uint4 srow = *(const uint4*)(xlh + (size_t)i * 64 + r * 8);
    float s[8]; DECODE8(srow, s);
    float ps = 0.f;
    #pragma unroll
    for (int k = 0; k < 8; k++)
        ps = fmaf(att[k], fabsf(s[k] + xri[k]), ps);
    ps += __shfl_xor(ps, 1, 64);
    ps += __shfl_xor(ps, 2, 64);
    ps += __shfl_xor(ps, 4, 64);
    float es = fmaf(0.4f, ps, fmaf(0.6f, slp[i], sri06));
    float wself = __expf(fminf(es, 60.f));

    float acc[8];
    #pragma unroll
    for (int k = 0; k < 8; k++) acc[k] = wself * s[k];
    float denom = wself;

    const int e0 = rowptr[i], e1 = rowptr[i + 1];
    const int n = e1 - e0;
    const int nq = n >> 2;          // full quads
    int e = e0;

    // ---- software-pipelined quad loop: gathers for q+1 issued during q ----
    uint4 u0, u1, u2, u3;
    float sl0, sl1, sl2, sl3;
    if (nq > 0) {                   // prologue: load quad 0
        int s0 = col[e], s1 = col[e + 1], s2 = col[e + 2], s3 = col[e + 3];
        sl0 = slp[s0]; sl1 = slp[s1]; sl2 = slp[s2]; sl3 = slp[s3];
        u0 = *(const uint4*)(xlh + (size_t)s0 * 64 + r * 8);
        u1 = *(const uint4*)(xlh + (size_t)s1 * 64 + r * 8);
        u2 = *(const uint4*)(xlh + (size_t)s2 * 64 + r * 8);
        u3 = *(const uint4*)(xlh + (size_t)s3 * 64 + r * 8);
    }
    for (int q = 1; q < nq; q++) {
        int t0 = col[e + 4], t1 = col[e + 5], t2 = col[e + 6], t3 = col[e + 7];
        float A[8], B[8], C[8], D[8];
        DECODE8(u0, A); DECODE8(u1, B); DECODE8(u2, C); DECODE8(u3, D);
        float p0 = 0.f, p1 = 0.f, p2 = 0.f, p3 = 0.f;
        #pragma unroll
        for (int k = 0; k < 8; k++) {
            p0 = fmaf(att[k], fabsf(A[k] + xri[k]), p0);
            p1 = fmaf(att[k], fabsf(B[k] + xri[k]), p1);
            p2 = fmaf(att[k], fabsf(C[k] + xri[k]), p2);
            p3 = fmaf(att[k], fabsf(D[k] + xri[k]), p3);
        }
        uint4 v0 = *(const uint4*)(xlh + (size_t)t0 * 64 + r * 8);
        uint4 v1 = *(const uint4*)(xlh + (size_t)t1 * 64 + r * 8);
        uint4 v2 = *(const uint4*)(xlh + (size_t)t2 * 64 + r * 8);
        uint4 v3 = *(const uint4*)(xlh + (size_t)t3 * 64 + r * 8);
        float m0 = slp[t0], m1 = slp[t1], m2 = slp[t2], m3 = slp[t3];
        p0 += __shfl_xor(p0, 1, 64);  p1 += __shfl_xor(p1, 1, 64);
        p2 += __shfl_xor(p2, 1, 64);  p3 += __shfl_xor(p3, 1, 64);
        p0 += __shfl_xor(p0, 2, 64);  p1 += __shfl_xor(p1, 2, 64);
        p2 += __shfl_xor(p2, 2, 64);  p3 += __shfl_xor(p3, 2, 64);
        p0 += __shfl_xor(p0, 4, 64);  p1 += __shfl_xor(p1, 4, 64);
        p2 += __shfl_xor(p2, 4, 64);  p3 += __shfl_xor(p3, 4, 64);
        float w0 = __expf(fminf(fmaf(0.4f, p0, fmaf(0.6f, sl0, sri06)), 60.f));
        float w1 = __expf(fminf(fmaf(0.4f, p1, fmaf(0.6f, sl1, sri06)), 60.f));
        float w2 = __expf(fminf(fmaf(0.4f, p2, fmaf(0.6f, sl2, sri06)), 60.f));
        float w3 = __expf(fminf(fmaf(0.4f, p3, fmaf(0.6f, sl3, sri06)), 60.f));
        #pragma unroll
        for (int k = 0; k < 8; k++) {
            acc[k] = fmaf(w0, A[k], acc[k]);
            acc[k] = fmaf(w1, B[k], acc[k]);
            acc[k] = fmaf(w2, C[k], acc[k]);
            acc[k] = fmaf(w3, D[k], acc[k]);
        }
        denom += (w0 + w1) + (w2 + w3);
        u0 = v0; u1 = v1; u2 = v2; u3 = v3;
        sl0 = m0; sl1 = m1; sl2 = m2; sl3 = m3;
        e += 4;
    }
    if (nq > 0) {                   // epilogue quad
        QUAD_BODY(u0, u1, u2, u3, sl0, sl1, sl2, sl3);
        e += 4;
    }

    // ---- 2-edge tail ----
    if (e + 2 <= e1) {
        int sa = col[e];
        int sb = col[e + 1];
        float sla = slp[sa], slb = slp[sb];
        uint4 ua = *(const uint4*)(xlh + (size_t)sa * 64 + r * 8);
        uint4 ub = *(const uint4*)(xlh + (size_t)sb * 64 + r * 8);
        float A[8], B[8];
        DECODE8(ua, A);
        DECODE8(ub, B);

        float pa = 0.f, pb = 0.f;
        #pragma unroll
        for (int k = 0; k < 8; k++) {
            pa = fmaf(att[k], fabsf(A[k] + xri[k]), pa);
            pb = fmaf(att[k], fabsf(B[k] + xri[k]), pb);
        }
        pa += __shfl_xor(pa, 1, 64);  pb += __shfl_xor(pb, 1, 64);
        pa += __shfl_xor(pa, 2, 64);  pb += __shfl_xor(pb, 2, 64);
        pa += __shfl_xor(pa, 4, 64);  pb += __shfl_xor(pb, 4, 64);

        float wa = __expf(fminf(fmaf(0.4f, pa, fmaf(0.6f, sla, sri06)), 60.f));
        float wb = __expf(fminf(fmaf(0.4f, pb, fmaf(0.6f, slb, sri06)), 60.f));

        #pragma unroll
        for (int k = 0; k < 8; k++) {
            acc[k] = fmaf(wa, A[k], acc[k]);
            acc[k] = fmaf(wb, B[k], acc[k]);
        }
        denom += wa + wb;
        e += 2;
    }

    // ---- 1-edge tail ----
    if (e < e1) {
        int sa = col[e];
        float sla = slp[sa];
        uint4 ua = *(const uint4*)(xlh + (size_t)sa * 64 + r * 8);
        float A[8];
        DECODE8(ua, A);

        float pa = 0.f;
        #pragma unroll
        for (int k = 0; k < 8; k++)
            pa = fmaf(att[k], fabsf(A[k] + xri[k]), pa);
        pa += __shfl_xor(pa, 1, 64);
        pa += __shfl_xor(pa, 2, 64);
        pa += __shfl_xor(pa, 4, 64);

        float wa = __expf(fminf(fmaf(0.4f, pa, fmaf(0.6f, sla, sri06)), 60.f));

        #pragma unroll
        for (int k = 0; k < 8; k++)
            acc[k] = fmaf(wa, A[k], acc[k]);
        denom += wa;
    }

    // ---- epilogue ----
    float inv = 1.f / denom;
    float4 bfa = *(const float4*)(bf + r * 8);
    float4 bfb = *(const float4*)(bf + r * 8 + 4);
    float h0 = fmaxf(fmaf(acc[0], inv, bfa.x), 0.f);
    float h1 = fmaxf(fmaf(acc[1], inv, bfa.y), 0.f);
    float h2 = fmaxf(fmaf(acc[2], inv, bfa.z), 0.f);
    float h3 = fmaxf(fmaf(acc[3], inv, bfa.w), 0.f);
    float h4 = fmaxf(fmaf(acc[4], inv, bfb.x), 0.f);
    float h5 = fmaxf(fmaf(acc[5], inv, bfb.y), 0.f);
    float h6 = fmaxf(fmaf(acc[6], inv, bfb.z), 0.f);
    float h7 = fmaxf(fmaf(acc[7], inv, bfb.w), 0.f);

    if constexpr (!LAST) {
        float* op = hout + (size_t)i * 64 + r * 8;
        *(float4*)(op)     = make_float4(h0, h1, h2, h3);
        *(float4*)(op + 4) = make_float4(h4, h5, h6, h7);
    } else {
        // fused readout: res[o] = sum_k h[k]*Wro[o][k]; reduce over octets r
        float hreg[8] = { h0, h1, h2, h3, h4, h5, h6, h7 };
        float res[OUTD];
        #pragma unroll
        for (int o = 0; o < OUTD; o++) res[o] = 0.f;
        #pragma unroll
        for (int j = 0; j < 8; j++) {
            float hv = hreg[j];
            #pragma unroll
            for (int o = 0; o < OUTD; o++)
                res[o] = fmaf(hv, wsh_[o * 64 + r * 8 + j], res[o]);
        }
        #pragma unroll
        for (int o = 0; o < OUTD; o++) {
            res[o] += __shfl_xor(res[o], 1, 64);
            res[o] += __shfl_xor(res[o], 2, 64);
            res[o] += __shfl_xor(res[o], 4, 64);
        }
        const int f = flagp[0];
        if (r < 5) {
            float lo = res[2 * r]     + bsh_[2 * r];
            float hi = res[2 * r + 1] + bsh_[2 * r + 1];
            if (f) {
                bf16 blo = __float2bfloat16(lo);
                bf16 bhi = __float2bfloat16(hi);
                unsigned u = ((unsigned)*(unsigned short*)&bhi << 16) |
                             (unsigned)*(unsigned short*)&blo;
                ((unsigned*)out)[(size_t)i * 5 + r] = u;
            } else {
                ((float2*)out)[(size_t)i * 5 + r] = make_float2(lo, hi);
            }
        }
    }
}

extern "C" void kernel_launch(void* const* d_in, const int* in_sizes, int n_in,
                              void* d_out, int out_size, void* d_ws, size_t ws_size,
                              hipStream_t stream) {
    const void* x   = d_in[0];
    const int* ei   = (const int*)d_in[1];
    const void* Wl0 = d_in[3];  const void* bl0 = d_in[4];
    const void* Wr0 = d_in[5];  const void* br0 = d_in[6];
    const void* at0 = d_in[7];  const void* b0  = d_in[8];
    const void* Wl1 = d_in[9];  const void* bl1 = d_in[10];
    const void* Wr1 = d_in[11]; const void* br1 = d_in[12];
    const void* at1 = d_in[13]; const void* b1  = d_in[14];
    const void* Wl2 = d_in[15]; const void* bl2 = d_in[16];
    const void* Wr2 = d_in[17]; const void* br2 = d_in[18];
    const void* at2 = d_in[19]; const void* b2  = d_in[20];
    const void* Wro = d_in[21]; const void* bro = d_in[22];

    const int* srcArr = ei;
    const int* dstArr = ei + EE;

    float* wf = (float*)d_ws;
    __half* Wh0  = (__half*)wf;               // 16384 halves (slot 16384 floats)
    __half* Wh1  = (__half*)(wf + 16384);     // 8192 halves
    __half* Wh2  = (__half*)(wf + 24576);     // 8192 halves
    float* small = wf + 32768;                // 1536
    int*   flag  = (int*)(wf + 34304);        // pad 64
    int*   rowptr = (int*)(wf + 34368);       // 80001 (pad 80128)
    int*   bsums  = (int*)(wf + 114496);      // 512
    int*   fillc  = (int*)(wf + 115008);      // 80000 (per-dst counts)
    int*   bucket_cnt  = (int*)(wf + 195008); // 128
    int*   bucket_base = (int*)(wf + 195136); // 128 (+1 used)
    int*   chunkcnt    = (int*)(wf + 195264); // NBUK*NCH = 49375 (pad 49472)
    int2*  part   = (int2*)(wf + 244736);     // EE int2 = 2560000 ints
    int*   col    = (int*)(wf + 2804736);     // EE ints = 1280000
    float* slp    = wf + 4084736;             // 80000
    float* srp    = wf + 4164736;             // 80000
    int*   order  = (int*)(wf + 4244736);     // 80000
    __half* xlh   = (__half*)(wf + 5364736);  // NN*64 halves = 2560000 floats
    float* xr = wf + 7924736;                 // 5120000
    float* hA = xr + (size_t)NN * 64;         // 5120000

    float* biasLR0 = small;        float* biasLR1 = small + 128; float* biasLR2 = small + 256;
    float* attf0 = small + 384;    float* attf1 = small + 448;   float* attf2 = small + 512;
    float* bf0   = small + 576;    float* bf1   = small + 640;   float* bf2   = small + 704;
    float* WROf  = small + 768;    float* brof  = small + 1408;

    detect_kernel<<<dim3(1), dim3(64), 0, stream>>>((const unsigned*)Wl0, flag);

    preconvert<<<dim3(134), dim3(256), 0, stream>>>(
        Wl0, Wr0, Wl1, Wr1, Wl2, Wr2, bl0, br0, bl1, br1, bl2, br2,
        at0, at1, at2, b0, b1, b2, Wro, bro, Wh0, Wh1, Wh2, small, flag);

    // deterministic edge sort + CSR
    chunkhist_kernel<<<dim3(NCH), dim3(256), 0, stream>>>(dstArr, chunkcnt);
    cscan_kernel<<<dim3(NBUK), dim3(1024), 0, stream>>>(chunkcnt, bucket_cnt);
    bscan_kernel<<<dim3(1), dim3(128), 0, stream>>>(bucket_cnt, bucket_base);
    part_kernel<<<dim3(NCH), dim3(256), 0, stream>>>(srcArr, dstArr, chunkcnt, bucket_base, part);
    hist_part_kernel<<<dim3(NBUK), dim3(256), 0, stream>>>(part, bucket_base, fillc);
    scan1<<<dim3(313), dim3(256), 0, stream>>>(fillc, rowptr, bsums);
    scan2<<<dim3(1), dim3(512), 0, stream>>>(bsums, 313);
    scan3<<<dim3(313), dim3(256), 0, stream>>>(rowptr, bsums);
    wprep_kernel<<<dim3(NN / WND), dim3(256), 0, stream>>>(fillc, order);
    scatter2_kernel<<<dim3(NBUK), dim3(256), 0, stream>>>(part, bucket_base, rowptr, col);

    // layer 0
    lin_mfma<128, true><<<dim3(NN / 64), dim3(256), 0, stream>>>(x, Wh0, biasLR0, attf0, xlh, xr, slp, srp, flag);
    agg9_kernel<0><<<dim3(NN / 32), dim3(256), 0, stream>>>(xlh, xr, slp, srp, attf0, bf0, rowptr, col, order, hA, nullptr, nullptr, nullptr, flag);
    // layer 1
    lin_mfma<64, false><<<dim3(NN / 64), dim3(256), 0, stream>>>(hA, Wh1, biasLR1, attf1, xlh, xr, slp, srp, flag);
    agg9_kernel<0><<<dim3(NN / 32), dim3(256), 0, stream>>>(xlh, xr, slp, srp, attf1, bf1, rowptr, col, order, hA, nullptr, nullptr, nullptr, flag);
    // layer 2 + fused readout
    lin_mfma<64, false><<<dim3(NN / 64), dim3(256), 0, stream>>>(hA, Wh2, biasLR2, attf2, xlh, xr, slp, srp, flag);
    agg9_kernel<1><<<dim3(NN / 32), dim3(256), 0, stream>>>(xlh, xr, slp, srp, attf2, bf2, rowptr, col, order, nullptr, WROf, brof, d_out, flag);
}

// Round 10
// 369.966 us; speedup vs baseline: 1.0218x; 1.0006x over previous
//
#include <hip/hip_runtime.h>
#include <hip/hip_bf16.h>
#include <hip/hip_fp16.h>

// GATv2 3-layer, N=80000 E=1280000 FIN=128 H=64 OUT=10.
// Round 24: agg10 — slp gather eliminated algebraically:
//   q = sum_k att_k*(xl[src]+xr[i]) = sl[src]+sr[i], so e = 0.6q + 0.4p with
//   p = sum att|u|. Computing q in the same fma pass (+8 fma, +3 shfl/edge)
//   deletes 1 of 3 random requests per edge (slp line gathers, ~82MB logical)
//   and the sl/sr epilogue+stores in lin_mfma. VALU floor << latency budget.
// R9 fused readout kept. Rest identical.

#define NN 80000
#define EE 1280000
#define FIN 128
#define HH 64
#define OUTD 10
#define NBUK 79            // dst>>10 buckets (79*1024 >= 80000)
#define PCH 2048           // edges per partition chunk
#define NCH 625            // EE / PCH
#define WND 2000           // degree-sort window (40 * 2000 = 80000)

typedef __hip_bfloat16 bf16;
typedef _Float16 f16x8 __attribute__((ext_vector_type(8)));
typedef float f32x4 __attribute__((ext_vector_type(4)));

__device__ __forceinline__ float ldw(const void* p, int i, int f) {
    return f ? __bfloat162float(((const bf16*)p)[i]) : ((const float*)p)[i];
}

// ---------------- dtype detect ----------------
__global__ void detect_kernel(const unsigned* __restrict__ w, int* __restrict__ flag) {
    int lane = threadIdx.x;
    int big = 0;
    for (int i = lane; i < 2048; i += 64) {
        unsigned u = w[i];
        float a = __uint_as_float(u << 16);
        float b = __uint_as_float(u & 0xffff0000u);
        if (!(fabsf(a) <= 1024.f)) big = 1;
        if (!(fabsf(b) <= 1024.f)) big = 1;
    }
    big = (__ballot(big) != 0ull) ? 1 : 0;
    if (lane == 0) flag[0] = big ? 0 : 1;     // 1 = bf16 storage, 0 = fp32
}

// ---------------- preconvert weights: Wh[j*F + k] fp16 ([j][k] = B-operand) --
__global__ void preconvert(
    const void* Wl0, const void* Wr0, const void* Wl1, const void* Wr1,
    const void* Wl2, const void* Wr2,
    const void* bl0, const void* br0, const void* bl1, const void* br1,
    const void* bl2, const void* br2,
    const void* att0, const void* att1, const void* att2,
    const void* b0, const void* b1, const void* b2,
    const void* Wro, const void* bro,
    __half* Wh0, __half* Wh1, __half* Wh2, float* small,
    const int* __restrict__ flagp)
{
    const int f = flagp[0];
    int t = blockIdx.x * 256 + threadIdx.x;
    if (t < 16384) {                        // L0: j<128, k<128
        int j = t & 127, k = t >> 7;
        float v = (j < 64) ? ldw(Wl0, j * 128 + k, f) : ldw(Wr0, (j - 64) * 128 + k, f);
        Wh0[j * 128 + k] = __float2half(v);
    } else if (t < 24576) {                 // L1: j<128, k<64
        int u = t - 16384; int j = u & 127, k = u >> 7;
        float v = (j < 64) ? ldw(Wl1, j * 64 + k, f) : ldw(Wr1, (j - 64) * 64 + k, f);
        Wh1[j * 64 + k] = __float2half(v);
    } else if (t < 32768) {                 // L2
        int u = t - 24576; int j = u & 127, k = u >> 7;
        float v = (j < 64) ? ldw(Wl2, j * 64 + k, f) : ldw(Wr2, (j - 64) * 64 + k, f);
        Wh2[j * 64 + k] = __float2half(v);
    } else if (t < 34304) {
        int s = t - 32768;
        const void* BL[3] = { bl0, bl1, bl2 };
        const void* BR[3] = { br0, br1, br2 };
        const void* AT[3] = { att0, att1, att2 };
        const void* BB[3] = { b0, b1, b2 };
        float v = 0.f;
        if (s < 384) {
            int l = s / 128, r = s % 128;
            v = (r < 64) ? ldw(BL[l], r, f) : ldw(BR[l], r - 64, f);
        } else if (s < 576) {
            int q = s - 384; v = ldw(AT[q / 64], q % 64, f);
        } else if (s < 768) {
            int q = s - 576; v = ldw(BB[q / 64], q % 64, f);
        } else if (s < 1408) {
            v = ldw(Wro, s - 768, f);
        } else if (s < 1418) {
            v = ldw(bro, s - 1408, f);
        } else return;
        small[s] = v;
    }
}

// ---------------- A: per-chunk bucket histogram ----------------
__global__ __launch_bounds__(256) void chunkhist_kernel(const int* __restrict__ dst,
                                                        int* __restrict__ chunkcnt)
{
    __shared__ int h[NBUK];
    const int tid = threadIdx.x, c = blockIdx.x;
    for (int i = tid; i < NBUK; i += 256) h[i] = 0;
    __syncthreads();
    const int e0 = c * PCH + tid * 8;
    int4 a = *(const int4*)(dst + e0);
    int4 b = *(const int4*)(dst + e0 + 4);
    atomicAdd(&h[a.x >> 10], 1); atomicAdd(&h[a.y >> 10], 1);
    atomicAdd(&h[a.z >> 10], 1); atomicAdd(&h[a.w >> 10], 1);
    atomicAdd(&h[b.x >> 10], 1); atomicAdd(&h[b.y >> 10], 1);
    atomicAdd(&h[b.z >> 10], 1); atomicAdd(&h[b.w >> 10], 1);
    __syncthreads();
    for (int i = tid; i < NBUK; i += 256) chunkcnt[i * NCH + c] = h[i];
}

// ---------------- B1: per-bucket exclusive scan over chunk counts ----------
__global__ __launch_bounds__(1024) void cscan_kernel(int* __restrict__ chunkcnt,
                                                     int* __restrict__ bucket_cnt)
{
    __shared__ int s[1024];
    const int b = blockIdx.x, t = threadIdx.x;
    int v = (t < NCH) ? chunkcnt[b * NCH + t] : 0;
    s[t] = v;
    __syncthreads();
    #pragma unroll
    for (int off = 1; off < 1024; off <<= 1) {
        int u = (t >= off) ? s[t - off] : 0;
        __syncthreads();
        s[t] += u;
        __syncthreads();
    }
    if (t < NCH) chunkcnt[b * NCH + t] = s[t] - v;
    if (t == NCH - 1) bucket_cnt[b] = s[t];
}

// ---------------- B2: scan buckets -> bucket_base ----------------
__global__ void bscan_kernel(const int* __restrict__ bucket_cnt,
                             int* __restrict__ bucket_base)
{
    __shared__ int sc[128];
    const int t = threadIdx.x;
    sc[t] = (t < NBUK) ? bucket_cnt[t] : 0;
    __syncthreads();
    #pragma unroll
    for (int off = 1; off < 128; off <<= 1) {
        int v = (t >= off) ? sc[t - off] : 0;
        __syncthreads();
        sc[t] += v;
        __syncthreads();
    }
    if (t < NBUK) bucket_base[t] = (t == 0) ? 0 : sc[t - 1];
    if (t == 0) bucket_base[NBUK] = sc[NBUK - 1];
}

// ---------------- C: deterministic partition into buckets -------------------
__global__ __launch_bounds__(256) void part_kernel(const int* __restrict__ src,
                                                   const int* __restrict__ dst,
                                                   const int* __restrict__ chunkcnt,
                                                   const int* __restrict__ bucket_base,
                                                   int2* __restrict__ part)
{
    __shared__ int hcnt[NBUK];
    __shared__ int sc[128];
    __shared__ int hbase[NBUK + 1];
    __shared__ int hpos[NBUK];
    __shared__ int hgb[NBUK];
    __shared__ int2 stage[PCH];
    const int tid = threadIdx.x, c = blockIdx.x;

    for (int i = tid; i < NBUK; i += 256) hcnt[i] = 0;
    __syncthreads();

    const int e0 = c * PCH + tid * 8;
    int4 sa = *(const int4*)(src + e0);
    int4 sb = *(const int4*)(src + e0 + 4);
    int4 da = *(const int4*)(dst + e0);
    int4 db = *(const int4*)(dst + e0 + 4);
    int dv[8] = { da.x, da.y, da.z, da.w, db.x, db.y, db.z, db.w };
    int sv[8] = { sa.x, sa.y, sa.z, sa.w, sb.x, sb.y, sb.z, sb.w };
    #pragma unroll
    for (int u = 0; u < 8; u++) atomicAdd(&hcnt[dv[u] >> 10], 1);
    __syncthreads();

    if (tid < 128) sc[tid] = (tid < NBUK) ? hcnt[tid] : 0;
    __syncthreads();
    #pragma unroll
    for (int off = 1; off < 128; off <<= 1) {
        int v = (tid < 128 && tid >= off) ? sc[tid - off] : 0;
        __syncthreads();
        if (tid < 128) sc[tid] += v;
        __syncthreads();
    }
    if (tid < NBUK) {
        int b = (tid == 0) ? 0 : sc[tid - 1];
        hbase[tid] = b;
        hpos[tid] = b;
        hgb[tid] = bucket_base[tid] + chunkcnt[tid * NCH + c];
    }
    if (tid == 0) hbase[NBUK] = PCH;
    __syncthreads();

    #pragma unroll
    for (int u = 0; u < 8; u++) {
        int p = atomicAdd(&hpos[dv[u] >> 10], 1);
        stage[p] = make_int2(sv[u], dv[u]);
    }
    __syncthreads();

    for (int s = tid; s < PCH; s += 256) {
        int lo = 0, hi = NBUK;
        #pragma unroll
        for (int it = 0; it < 7; it++) {
            int mid = (lo + hi) >> 1;
            if (hbase[mid] <= s) lo = mid; else hi = mid;
        }
        part[hgb[lo] + (s - hbase[lo])] = stage[s];
    }
}

// ---------------- fine hist: one block per bucket, LDS counters -------------
__global__ __launch_bounds__(256) void hist_part_kernel(const int2* __restrict__ part,
                                                        const int* __restrict__ bucket_base,
                                                        int* __restrict__ cnt)
{
    __shared__ int lcnt[1024];
    const int b = blockIdx.x, tid = threadIdx.x;
    const int dbase = b << 10;
    for (int i = tid; i < 1024; i += 256) lcnt[i] = 0;
    __syncthreads();
    const int eb = bucket_base[b], ee = bucket_base[b + 1];
    for (int e = eb + tid; e < ee; e += 256)
        atomicAdd(&lcnt[part[e].y - dbase], 1);
    __syncthreads();
    const int nd = min(1024, NN - dbase);
    for (int i = tid; i < nd; i += 256) cnt[dbase + i] = lcnt[i];
}

// ---------------- scans ----------------
__global__ void scan1(const int* __restrict__ cnt, int* __restrict__ rowptr,
                      int* __restrict__ bsums) {
    __shared__ int sh[256];
    int i = blockIdx.x * 256 + threadIdx.x;
    int tid = threadIdx.x;
    int c = (i < NN) ? cnt[i] : 0;
    sh[tid] = c;
    __syncthreads();
    #pragma unroll
    for (int off = 1; off < 256; off <<= 1) {
        int t = (tid >= off) ? sh[tid - off] : 0;
        __syncthreads();
        sh[tid] += t;
        __syncthreads();
    }
    if (i < NN) rowptr[i + 1] = sh[tid];
    if (tid == 255) bsums[blockIdx.x] = sh[255];
}

__global__ void scan2(int* __restrict__ bsums, int nb) {
    __shared__ int sh[512];
    int t = threadIdx.x;
    sh[t] = (t < nb) ? bsums[t] : 0;
    __syncthreads();
    #pragma unroll
    for (int off = 1; off < 512; off <<= 1) {
        int v = (t >= off) ? sh[t - off] : 0;
        __syncthreads();
        sh[t] += v;
        __syncthreads();
    }
    if (t < nb) bsums[t] = sh[t];
}

__global__ void scan3(int* __restrict__ rowptr, const int* __restrict__ bsums) {
    int i = blockIdx.x * 256 + threadIdx.x;
    if (i == 0) rowptr[0] = 0;
    int add = (blockIdx.x == 0) ? 0 : bsums[blockIdx.x - 1];
    if (i < NN) rowptr[i + 1] += add;
}

// ---------------- wprep: window-local degree counting sort (all LDS) --------
// One block per 2000-node window; descending-degree order within window.
__global__ __launch_bounds__(256) void wprep_kernel(const int* __restrict__ fillc,
                                                    int* __restrict__ order)
{
    __shared__ int h[64];
    const int w0 = blockIdx.x * WND;
    const int tid = threadIdx.x;
    if (tid < 64) h[tid] = 0;
    __syncthreads();
    int bin[8];
    #pragma unroll
    for (int u = 0; u < 8; u++) {
        int t = tid + u * 256;
        if (t < WND) {
            int b = 63 - min(fillc[w0 + t], 63);   // descending degree
            bin[u] = b;
            atomicAdd(&h[b], 1);
        } else bin[u] = -1;
    }
    __syncthreads();
    if (tid == 0) {                                 // 64-bin exclusive scan
        int run = 0;
        #pragma unroll
        for (int b = 0; b < 64; b++) { int c = h[b]; h[b] = run; run += c; }
    }
    __syncthreads();
    #pragma unroll
    for (int u = 0; u < 8; u++) {
        int t = tid + u * 256;
        if (t < WND) {
            int p = atomicAdd(&h[bin[u]], 1);
            order[w0 + p] = w0 + t;
        }
    }
}

// ---------------- P2: fine scatter, one block per bucket --------------------
// col stores src only (agg never needs dst; it's implicit).
__global__ __launch_bounds__(256) void scatter2_kernel(const int2* __restrict__ part,
                                                       const int* __restrict__ bucket_base,
                                                       const int* __restrict__ rowptr,
                                                       int* __restrict__ col)
{
    __shared__ int lfill[1024];
    const int b = blockIdx.x, tid = threadIdx.x;
    const int dbase = b << 10;
    const int nd = min(1024, NN - dbase);
    for (int i = tid; i < nd; i += 256) lfill[i] = rowptr[dbase + i];
    __syncthreads();
    const int eb = bucket_base[b], ee = bucket_base[b + 1];
    for (int e = eb + tid; e < ee; e += 256) {
        int2 sd = part[e];
        int pos = atomicAdd(&lfill[sd.y - dbase], 1);
        col[pos] = sd.x;
    }
}

// ---------------- linear via MFMA f16: [64 x F] @ [F x 128] -----------------
// A staged fp16 in LDS, XOR-swizzled (octet ^= row&7). B = Wh[j][k] from L1.
// C/D: col=lane&15, row=(lane>>4)*4+reg; A: [m=lane&15][k=quad*8+j];
// B: [n=lane&15][k=quad*8+j] (k-major per lane).
#define ELX_S 72           // epilogue xl row stride (fp16)
#define EXR_S 68           // epilogue xr row stride (fp32)
template<int F, bool L0>
__global__ __launch_bounds__(256) void lin_mfma(const void* __restrict__ hin_,
                                                const __half* __restrict__ Wh,
                                                const float* __restrict__ biasLR,
                                                __half* __restrict__ xlh,
                                                float* __restrict__ xr,
                                                const int* __restrict__ flagp)
{
    __shared__ __align__(16) char lds[64 * ELX_S * 2 + 64 * EXR_S * 4]; // 26624 B
    _Float16* xs  = (_Float16*)lds;                    // stage: 64*F fp16 (<=16KB)
    _Float16* eXL = (_Float16*)lds;                    // epilogue xl 64x72 fp16
    float*    eXR = (float*)(lds + 64 * ELX_S * 2);    // epilogue xr 64x68 fp32

    const int tid = threadIdx.x;
    const int nb = blockIdx.x * 64;
    constexpr int OPR = F / 8;     // octets per row

    // ---- stage h -> swizzled fp16 LDS ----
    if (L0 && flagp[0]) {
        const uint4* hp = (const uint4*)hin_;
        for (int c = tid; c < 64 * OPR; c += 256) {
            int row = c / OPR, oct = c % OPR;
            uint4 u = hp[((size_t)(nb + row) * F + oct * 8) >> 3];
            unsigned ww[4] = { u.x, u.y, u.z, u.w };
            _Float16 v[8];
            #pragma unroll
            for (int p = 0; p < 4; p++) {
                v[2 * p]     = (_Float16)__uint_as_float(ww[p] << 16);
                v[2 * p + 1] = (_Float16)__uint_as_float(ww[p] & 0xffff0000u);
            }
            int so = oct ^ (row & 7);
            *(f16x8*)&xs[row * F + so * 8] = *(f16x8*)v;
        }
    } else {
        const float4* hp = (const float4*)hin_;
        for (int c = tid; c < 64 * OPR; c += 256) {
            int row = c / OPR, oct = c % OPR;
            size_t base = ((size_t)(nb + row) * F + oct * 8) >> 2;
            float4 a = hp[base], b = hp[base + 1];
            _Float16 v[8] = { (_Float16)a.x, (_Float16)a.y, (_Float16)a.z, (_Float16)a.w,
                              (_Float16)b.x, (_Float16)b.y, (_Float16)b.z, (_Float16)b.w };
            int so = oct ^ (row & 7);
            *(f16x8*)&xs[row * F + so * 8] = *(f16x8*)v;
        }
    }
    __syncthreads();

    const int w = tid >> 6;
    const int lane = tid & 63;
    const int n = lane & 15;
    const int quad = lane >> 4;
    constexpr int NS = F / 32;

    f16x8 afr[NS];
    #pragma unroll
    for (int s = 0; s < NS; s++) {
        int o = (s * 4 + quad) ^ (n & 7);
        afr[s] = *(const f16x8*)&xs[(w * 16 + n) * F + o * 8];
    }
    __syncthreads();   // xs dead; LDS reused for epilogue

    const _Float16* Whf = (const _Float16*)Wh;
    #pragma unroll
    for (int ct = 0; ct < 8; ct++) {
        float bv = biasLR[ct * 16 + n];
        f32x4 acc = { bv, bv, bv, bv };
        #pragma unroll
        for (int s = 0; s < NS; s++) {
            f16x8 bfr = *(const f16x8*)&Whf[(size_t)(ct * 16 + n) * F + s * 32 + quad * 8];
            acc = __builtin_amdgcn_mfma_f32_16x16x32_f16(afr[s], bfr, acc, 0, 0, 0);
        }
        int rbase = w * 16 + quad * 4;
        if (ct < 4) {
            #pragma unroll
            for (int rg = 0; rg < 4; rg++)
                eXL[(rbase + rg) * ELX_S + ct * 16 + n] = (_Float16)acc[rg];
        } else {
            #pragma unroll
            for (int rg = 0; rg < 4; rg++)
                eXR[(rbase + rg) * EXR_S + (ct - 4) * 16 + n] = acc[rg];
        }
    }
    __syncthreads();

    // ---- vectorized writeout ----
    for (int c = tid; c < 512; c += 256) {          // xl: 64 rows x 64 fp16
        int row = c >> 3, oct = c & 7;
        *(uint4*)&xlh[(size_t)(nb + row) * 64 + oct * 8] =
            *(const uint4*)&eXL[row * ELX_S + oct * 8];
    }
    for (int c = tid; c < 1024; c += 256) {         // xr: 64 rows x 64 fp32
        int row = c >> 4, q4 = c & 15;
        *(float4*)&xr[(size_t)(nb + row) * 64 + q4 * 4] =
            *(const float4*)&eXR[row * EXR_S + q4 * 4];
    }
}

// ---------------- fused score+aggregate (+ optional fused readout) ----------
// score: u = xl[src]+xr[i]; p = sum att|u|; q = sum att*u (= sl[src]+sr[i]);
//        e = 0.6q + 0.4p  (no slp/srp gathers needed)
#define DECODE8(U, D) { \
    float2 _f0 = __half22float2(*(__half2*)&U.x); \
    float2 _f1 = __half22float2(*(__half2*)&U.y); \
    float2 _f2 = __half22float2(*(__half2*)&U.z); \
    float2 _f3 = __half22float2(*(__half2*)&U.w); \
    D[0]=_f0.x; D[1]=_f0.y; D[2]=_f1.x; D[3]=_f1.y; \
    D[4]=_f2.x; D[5]=_f2.y; D[6]=_f3.x; D[7]=_f3.y; }

// compute one quad (data in u0..u3) and accumulate
#define QUAD_BODY(U0, U1, U2, U3) { \
    float A[8], B[8], C[8], D[8]; \
    DECODE8(U0, A); DECODE8(U1, B); DECODE8(U2, C); DECODE8(U3, D); \
    float p0 = 0.f, p1 = 0.f, p2 = 0.f, p3 = 0.f; \
    float q0 = 0.f, q1 = 0.f, q2 = 0.f, q3 = 0.f; \
    _Pragma("unroll") \
    for (int k = 0; k < 8; k++) { \
        float ua = A[k] + xri[k], ub = B[k] + xri[k]; \
        float uc = C[k] + xri[k], ud = D[k] + xri[k]; \
        p0 = fmaf(att[k], fabsf(ua), p0); q0 = fmaf(att[k], ua, q0); \
        p1 = fmaf(att[k], fabsf(ub), p1); q1 = fmaf(att[k], ub, q1); \
        p2 = fmaf(att[k], fabsf(uc), p2); q2 = fmaf(att[k], uc, q2); \
        p3 = fmaf(att[k], fabsf(ud), p3); q3 = fmaf(att[k], ud, q3); \
    } \
    p0 += __shfl_xor(p0, 1, 64);  p1 += __shfl_xor(p1, 1, 64); \
    p2 += __shfl_xor(p2, 1, 64);  p3 += __shfl_xor(p3, 1, 64); \
    q0 += __shfl_xor(q0, 1, 64);  q1 += __shfl_xor(q1, 1, 64); \
    q2 += __shfl_xor(q2, 1, 64);  q3 += __shfl_xor(q3, 1, 64); \
    p0 += __shfl_xor(p0, 2, 64);  p1 += __shfl_xor(p1, 2, 64); \
    p2 += __shfl_xor(p2, 2, 64);  p3 += __shfl_xor(p3, 2, 64); \
    q0 += __shfl_xor(q0, 2, 64);  q1 += __shfl_xor(q1, 2, 64); \
    q2 += __shfl_xor(q2, 2, 64);  q3 += __shfl_xor(q3, 2, 64); \
    p0 += __shfl_xor(p0, 4, 64);  p1 += __shfl_xor(p1, 4, 64); \
    p2 += __shfl_xor(p2, 4, 64);  p3 += __shfl_xor(p3, 4, 64); \
    q0 += __shfl_xor(q0, 4, 64);  q1 += __shfl_xor(q1, 4, 64); \
    q2 += __shfl_xor(q2, 4, 64);  q3 += __shfl_xor(q3, 4, 64); \
    float w0 = __expf(fminf(fmaf(0.6f, q0, 0.4f * p0), 60.f)); \
    float w1 = __expf(fminf(fmaf(0.6f, q1, 0.4f * p1), 60.f)); \
    float w2 = __expf(fminf(fmaf(0.6f, q2, 0.4f * p2), 60.f)); \
    float w3 = __expf(fminf(fmaf(0.6f, q3, 0.4f * p3), 60.f)); \
    _Pragma("unroll") \
    for (int k = 0; k < 8; k++) { \
        acc[k] = fmaf(w0, A[k], acc[k]); \
        acc[k] = fmaf(w1, B[k], acc[k]); \
        acc[k] = fmaf(w2, C[k], acc[k]); \
        acc[k] = fmaf(w3, D[k], acc[k]); \
    } \
    denom += (w0 + w1) + (w2 + w3); \
}

template<int LAST>
__global__ __launch_bounds__(256) void agg10_kernel(const __half* __restrict__ xlh,
                                                    const float* __restrict__ xr,
                                                    const float* __restrict__ attf,
                                                    const float* __restrict__ bf,
                                                    const int* __restrict__ rowptr,
                                                    const int* __restrict__ col,
                                                    const int* __restrict__ order,
                                                    float* __restrict__ hout,
                                                    const float* __restrict__ WROf,
                                                    const float* __restrict__ brof,
                                                    void* __restrict__ out,
                                                    const int* __restrict__ flagp)
{
    __shared__ float wsh_[640];      // Wro [o*64+k] (LAST only)
    __shared__ float bsh_[OUTD];

    const int lane = threadIdx.x & 63;
    const int g = lane >> 3;        // group -> node within wave
    const int r = lane & 7;         // feature octet
    const int wid = blockIdx.x * 4 + (threadIdx.x >> 6);
    const int i = order[wid * 8 + g];   // window-degree-sorted node

    if constexpr (LAST) {
        for (int idx = threadIdx.x; idx < 640; idx += 256) wsh_[idx] = WROf[idx];
        if (threadIdx.x < OUTD) bsh_[threadIdx.x] = brof[threadIdx.x];
        __syncthreads();
    }

    float xri[8], att[8];
    {
        float4 xa = *(const float4*)(xr + (size_t)i * 64 + r * 8);
        float4 xb = *(const float4*)(xr + (size_t)i * 64 + r * 8 + 4);
        xri[0]=xa.x; xri[1]=xa.y; xri[2]=xa.z; xri[3]=xa.w;
        xri[4]=xb.x; xri[5]=xb.y; xri[6]=xb.z; xri[7]=xb.w;
        float4 aa = *(const float4*)(attf + r * 8);
        float4 ab = *(const float4*)(attf + r * 8 + 4);
        att[0]=aa.x; att[1]=aa.y; att[2]=aa.z; att[3]=aa.w;
        att[4]=ab.x; att[5]=ab.y; att[6]=ab.z; att[7]=ab.w;
    }

    // ---- self edge ----
    uint4 srow = *(const uint4*)(xlh + (size_t)i * 64 + r * 8);
    float s[8]; DECODE8(srow, s);
    float ps = 0.f, qs = 0.f;
    #pragma unroll
    for (int k = 0; k < 8; k++) {
        float u = s[k] + xri[k];
        ps = fmaf(att[k], fabsf(u), ps);
        qs = fmaf(att[k], u, qs);
    }
    ps += __shfl_xor(ps, 1, 64);  qs += __shfl_xor(qs, 1, 64);
    ps += __shfl_xor(ps, 2, 64);  qs += __shfl_xor(qs, 2, 64);
    ps += __shfl_xor(ps, 4, 64);  qs += __shfl_xor(qs, 4, 64);
    float wself = __expf(fminf(fmaf(0.6f, qs, 0.4f * ps), 60.f));

    float acc[8];
    #pragma unroll
    for (int k = 0; k < 8; k++) acc[k] = wself * s[k];
    float denom = wself;

    const int e0 = rowptr[i], e1 = rowptr[i + 1];
    const int n = e1 - e0;
    const int nq = n >> 2;          // full quads
    int e = e0;

    // ---- software-pipelined quad loop ----
    uint4 u0, u1, u2, u3;
    if (nq > 0) {                   // prologue: load quad 0
        int s0 = col[e], s1 = col[e + 1], s2 = col[e + 2], s3 = col[e + 3];
        u0 = *(const uint4*)(xlh + (size_t)s0 * 64 + r * 8);
        u1 = *(const uint4*)(xlh + (size_t)s1 * 64 + r * 8);
        u2 = *(const uint4*)(xlh + (size_t)s2 * 64 + r * 8);
        u3 = *(const uint4*)(xlh + (size_t)s3 * 64 + r * 8);
    }
    for (int q = 1; q < nq; q++) {
        int t0 = col[e + 4], t1 = col[e + 5], t2 = col[e + 6], t3 = col[e + 7];
        float A[8], B[8], C[8], D[8];
        DECODE8(u0, A); DECODE8(u1, B); DECODE8(u2, C); DECODE8(u3, D);
        float p0 = 0.f, p1 = 0.f, p2 = 0.f, p3 = 0.f;
        float q0 = 0.f, q1 = 0.f, q2 = 0.f, q3 = 0.f;
        #pragma unroll
        for (int k = 0; k < 8; k++) {
            float ua = A[k] + xri[k], ub = B[k] + xri[k];
            float uc = C[k] + xri[k], ud = D[k] + xri[k];
            p0 = fmaf(att[k], fabsf(ua), p0); q0 = fmaf(att[k], ua, q0);
            p1 = fmaf(att[k], fabsf(ub), p1); q1 = fmaf(att[k], ub, q1);
            p2 = fmaf(att[k], fabsf(uc), p2); q2 = fmaf(att[k], uc, q2);
            p3 = fmaf(att[k], fabsf(ud), p3); q3 = fmaf(att[k], ud, q3);
        }
        uint4 v0 = *(const uint4*)(xlh + (size_t)t0 * 64 + r * 8);
        uint4 v1 = *(const uint4*)(xlh + (size_t)t1 * 64 + r * 8);
        uint4 v2 = *(const uint4*)(xlh + (size_t)t2 * 64 + r * 8);
        uint4 v3 = *(const uint4*)(xlh + (size_t)t3 * 64 + r * 8);
        p0 += __shfl_xor(p0, 1, 64);  p1 += __shfl_xor(p1, 1, 64);
        p2 += __shfl_xor(p2, 1, 64);  p3 += __shfl_xor(p3, 1, 64);
        q0 += __shfl_xor(q0, 1, 64);  q1 += __shfl_xor(q1, 1, 64);
        q2 += __shfl_xor(q2, 1, 64);  q3 += __shfl_xor(q3, 1, 64);
        p0 += __shfl_xor(p0, 2, 64);  p1 += __shfl_xor(p1, 2, 64);
        p2 += __shfl_xor(p2, 2, 64);  p3 += __shfl_xor(p3, 2, 64);
        q0 += __shfl_xor(q0, 2, 64);  q1 += __shfl_xor(q1, 2, 64);
        q2 += __shfl_xor(q2, 2, 64);  q3 += __shfl_xor(q3, 2, 64);
        p0 += __shfl_xor(p0, 4, 64);  p1 += __shfl_xor(p1, 4, 64);
        p2 += __shfl_xor(p2, 4, 64);  p3 += __shfl_xor(p3, 4, 64);
        q0 += __shfl_xor(q0, 4, 64);  q1 += __shfl_xor(q1, 4, 64);
        q2 += __shfl_xor(q2, 4, 64);  q3 += __shfl_xor(q3, 4, 64);
        float w0 = __expf(fminf(fmaf(0.6f, q0, 0.4f * p0), 60.f));
        float w1 = __expf(fminf(fmaf(0.6f, q1, 0.4f * p1), 60.f));
        float w2 = __expf(fminf(fmaf(0.6f, q2, 0.4f * p2), 60.f));
        float w3 = __expf(fminf(fmaf(0.6f, q3, 0.4f * p3), 60.f));
        #pragma unroll
        for (int k = 0; k < 8; k++) {
            acc[k] = fmaf(w0, A[k], acc[k]);
            acc[k] = fmaf(w1, B[k], acc[k]);
            acc[k] = fmaf(w2, C[k], acc[k]);
            acc[k] = fmaf(w3, D[k], acc[k]);
        }
        denom += (w0 + w1) + (w2 + w3);
        u0 = v0; u1 = v1; u2 = v2; u3 = v3;
        e += 4;
    }
    if (nq > 0) {                   // epilogue quad
        QUAD_BODY(u0, u1, u2, u3);
        e += 4;
    }

    // ---- 2-edge tail ----
    if (e + 2 <= e1) {
        int sa = col[e];
        int sb = col[e + 1];
        uint4 ua = *(const uint4*)(xlh + (size_t)sa * 64 + r * 8);
        uint4 ub = *(const uint4*)(xlh + (size_t)sb * 64 + r * 8);
        float A[8], B[8];
        DECODE8(ua, A);
        DECODE8(ub, B);

        float pa = 0.f, pb = 0.f, qa = 0.f, qb = 0.f;
        #pragma unroll
        for (int k = 0; k < 8; k++) {
            float va = A[k] + xri[k];
            float vb = B[k] + xri[k];
            pa = fmaf(att[k], fabsf(va), pa); qa = fmaf(att[k], va, qa);
            pb = fmaf(att[k], fabsf(vb), pb); qb = fmaf(att[k], vb, qb);
        }
        pa += __shfl_xor(pa, 1, 64);  pb += __shfl_xor(pb, 1, 64);
        qa += __shfl_xor(qa, 1, 64);  qb += __shfl_xor(qb, 1, 64);
        pa += __shfl_xor(pa, 2, 64);  pb += __shfl_xor(pb, 2, 64);
        qa += __shfl_xor(qa, 2, 64);  qb += __shfl_xor(qb, 2, 64);
        pa += __shfl_xor(pa, 4, 64);  pb += __shfl_xor(pb, 4, 64);
        qa += __shfl_xor(qa, 4, 64);  qb += __shfl_xor(qb, 4, 64);

        float wa = __expf(fminf(fmaf(0.6f, qa, 0.4f * pa), 60.f));
        float wb = __expf(fminf(fmaf(0.6f, qb, 0.4f * pb), 60.f));

        #pragma unroll
        for (int k = 0; k < 8; k++) {
            acc[k] = fmaf(wa, A[k], acc[k]);
            acc[k] = fmaf(wb, B[k], acc[k]);
        }
        denom += wa + wb;
        e += 2;
    }

    // ---- 1-edge tail ----
    if (e < e1) {
        int sa = col[e];
        uint4 ua = *(const uint4*)(xlh + (size_t)sa * 64 + r * 8);
        float A[8];
        DECODE8(ua, A);

        float pa = 0.f, qa = 0.f;
        #pragma unroll
        for (int k = 0; k < 8; k++) {
            float va = A[k] + xri[k];
            pa = fmaf(att[k], fabsf(va), pa);
            qa = fmaf(att[k], va, qa);
        }
        pa += __shfl_xor(pa, 1, 64);  qa += __shfl_xor(qa, 1, 64);
        pa += __shfl_xor(pa, 2, 64);  qa += __shfl_xor(qa, 2, 64);
        pa += __shfl_xor(pa, 4, 64);  qa += __shfl_xor(qa, 4, 64);

        float wa = __expf(fminf(fmaf(0.6f, qa, 0.4f * pa), 60.f));

        #pragma unroll
        for (int k = 0; k < 8; k++)
            acc[k] = fmaf(wa, A[k], acc[k]);
        denom += wa;
    }

    // ---- epilogue ----
    float inv = 1.f / denom;
    float4 bfa = *(const float4*)(bf + r * 8);
    float4 bfb = *(const float4*)(bf + r * 8 + 4);
    float h0 = fmaxf(fmaf(acc[0], inv, bfa.x), 0.f);
    float h1 = fmaxf(fmaf(acc[1], inv, bfa.y), 0.f);
    float h2 = fmaxf(fmaf(acc[2], inv, bfa.z), 0.f);
    float h3 = fmaxf(fmaf(acc[3], inv, bfa.w), 0.f);
    float h4 = fmaxf(fmaf(acc[4], inv, bfb.x), 0.f);
    float h5 = fmaxf(fmaf(acc[5], inv, bfb.y), 0.f);
    float h6 = fmaxf(fmaf(acc[6], inv, bfb.z), 0.f);
    float h7 = fmaxf(fmaf(acc[7], inv, bfb.w), 0.f);

    if constexpr (!LAST) {
        float* op = hout + (size_t)i * 64 + r * 8;
        *(float4*)(op)     = make_float4(h0, h1, h2, h3);
        *(float4*)(op + 4) = make_float4(h4, h5, h6, h7);
    } else {
        // fused readout: res[o] = sum_k h[k]*Wro[o][k]; reduce over octets r
        float hreg[8] = { h0, h1, h2, h3, h4, h5, h6, h7 };
        float res[OUTD];
        #pragma unroll
        for (int o = 0; o < OUTD; o++) res[o] = 0.f;
        #pragma unroll
        for (int j = 0; j < 8; j++) {
            float hv = hreg[j];
            #pragma unroll
            for (int o = 0; o < OUTD; o++)
                res[o] = fmaf(hv, wsh_[o * 64 + r * 8 + j], res[o]);
        }
        #pragma unroll
        for (int o = 0; o < OUTD; o++) {
            res[o] += __shfl_xor(res[o], 1, 64);
            res[o] += __shfl_xor(res[o], 2, 64);
            res[o] += __shfl_xor(res[o], 4, 64);
        }
        const int f = flagp[0];
        if (r < 5) {
            float lo = res[2 * r]     + bsh_[2 * r];
            float hi = res[2 * r + 1] + bsh_[2 * r + 1];
            if (f) {
                bf16 blo = __float2bfloat16(lo);
                bf16 bhi = __float2bfloat16(hi);
                unsigned u = ((unsigned)*(unsigned short*)&bhi << 16) |
                             (unsigned)*(unsigned short*)&blo;
                ((unsigned*)out)[(size_t)i * 5 + r] = u;
            } else {
                ((float2*)out)[(size_t)i * 5 + r] = make_float2(lo, hi);
            }
        }
    }
}

extern "C" void kernel_launch(void* const* d_in, const int* in_sizes, int n_in,
                              void* d_out, int out_size, void* d_ws, size_t ws_size,
                              hipStream_t stream) {
    const void* x   = d_in[0];
    const int* ei   = (const int*)d_in[1];
    const void* Wl0 = d_in[3];  const void* bl0 = d_in[4];
    const void* Wr0 = d_in[5];  const void* br0 = d_in[6];
    const void* at0 = d_in[7];  const void* b0  = d_in[8];
    const void* Wl1 = d_in[9];  const void* bl1 = d_in[10];
    const void* Wr1 = d_in[11]; const void* br1 = d_in[12];
    const void* at1 = d_in[13]; const void* b1  = d_in[14];
    const void* Wl2 = d_in[15]; const void* bl2 = d_in[16];
    const void* Wr2 = d_in[17]; const void* br2 = d_in[18];
    const void* at2 = d_in[19]; const void* b2  = d_in[20];
    const void* Wro = d_in[21]; const void* bro = d_in[22];

    const int* srcArr = ei;
    const int* dstArr = ei + EE;

    float* wf = (float*)d_ws;
    __half* Wh0  = (__half*)wf;               // 16384 halves (slot 16384 floats)
    __half* Wh1  = (__half*)(wf + 16384);     // 8192 halves
    __half* Wh2  = (__half*)(wf + 24576);     // 8192 halves
    float* small = wf + 32768;                // 1536
    int*   flag  = (int*)(wf + 34304);        // pad 64
    int*   rowptr = (int*)(wf + 34368);       // 80001 (pad 80128)
    int*   bsums  = (int*)(wf + 114496);      // 512
    int*   fillc  = (int*)(wf + 115008);      // 80000 (per-dst counts)
    int*   bucket_cnt  = (int*)(wf + 195008); // 128
    int*   bucket_base = (int*)(wf + 195136); // 128 (+1 used)
    int*   chunkcnt    = (int*)(wf + 195264); // NBUK*NCH = 49375 (pad 49472)
    int2*  part   = (int2*)(wf + 244736);     // EE int2 = 2560000 ints
    int*   col    = (int*)(wf + 2804736);     // EE ints = 1280000
    int*   order  = (int*)(wf + 4244736);     // 80000
    __half* xlh   = (__half*)(wf + 5364736);  // NN*64 halves = 2560000 floats
    float* xr = wf + 7924736;                 // 5120000
    float* hA = xr + (size_t)NN * 64;         // 5120000

    float* biasLR0 = small;        float* biasLR1 = small + 128; float* biasLR2 = small + 256;
    float* attf0 = small + 384;    float* attf1 = small + 448;   float* attf2 = small + 512;
    float* bf0   = small + 576;    float* bf1   = small + 640;   float* bf2   = small + 704;
    float* WROf  = small + 768;    float* brof  = small + 1408;

    detect_kernel<<<dim3(1), dim3(64), 0, stream>>>((const unsigned*)Wl0, flag);

    preconvert<<<dim3(134), dim3(256), 0, stream>>>(
        Wl0, Wr0, Wl1, Wr1, Wl2, Wr2, bl0, br0, bl1, br1, bl2, br2,
        at0, at1, at2, b0, b1, b2, Wro, bro, Wh0, Wh1, Wh2, small, flag);

    // deterministic edge sort + CSR
    chunkhist_kernel<<<dim3(NCH), dim3(256), 0, stream>>>(dstArr, chunkcnt);
    cscan_kernel<<<dim3(NBUK), dim3(1024), 0, stream>>>(chunkcnt, bucket_cnt);
    bscan_kernel<<<dim3(1), dim3(128), 0, stream>>>(bucket_cnt, bucket_base);
    part_kernel<<<dim3(NCH), dim3(256), 0, stream>>>(srcArr, dstArr, chunkcnt, bucket_base, part);
    hist_part_kernel<<<dim3(NBUK), dim3(256), 0, stream>>>(part, bucket_base, fillc);
    scan1<<<dim3(313), dim3(256), 0, stream>>>(fillc, rowptr, bsums);
    scan2<<<dim3(1), dim3(512), 0, stream>>>(bsums, 313);
    scan3<<<dim3(313), dim3(256), 0, stream>>>(rowptr, bsums);
    wprep_kernel<<<dim3(NN / WND), dim3(256), 0, stream>>>(fillc, order);
    scatter2_kernel<<<dim3(NBUK), dim3(256), 0, stream>>>(part, bucket_base, rowptr, col);

    // layer 0
    lin_mfma<128, true><<<dim3(NN / 64), dim3(256), 0, stream>>>(x, Wh0, biasLR0, xlh, xr, flag);
    agg10_kernel<0><<<dim3(NN / 32), dim3(256), 0, stream>>>(xlh, xr, attf0, bf0, rowptr, col, order, hA, nullptr, nullptr, nullptr, flag);
    // layer 1
    lin_mfma<64, false><<<dim3(NN / 64), dim3(256), 0, stream>>>(hA, Wh1, biasLR1, xlh, xr, flag);
    agg10_kernel<0><<<dim3(NN / 32), dim3(256), 0, stream>>>(xlh, xr, attf1, bf1, rowptr, col, order, hA, nullptr, nullptr, nullptr, flag);
    // layer 2 + fused readout
    lin_mfma<64, false><<<dim3(NN / 64), dim3(256), 0, stream>>>(hA, Wh2, biasLR2, xlh, xr, flag);
    agg10_kernel<1><<<dim3(NN / 32), dim3(256), 0, stream>>>(xlh, xr, attf2, bf2, rowptr, col, order, nullptr, WROf, brof, d_out, flag);
}